// Round 2
// baseline (4799.936 us; speedup 1.0000x reference)
//
#include <hip/hip_runtime.h>
#include <math.h>

#define NV_   50000
#define T16_  16
#define NVT_  800000
#define NB_   120000
#define G_    16
#define P_    8
#define H_    512
#define W_    512

// ---- workspace layout (float element offsets) ----
// y34 region (51.2M floats) is reused after K5 for pre17/x17/y1819.
#define OF_Y34    0ul            // 51.2M  y3 then y4 in-place [K3..K5]
#define OF_Y2     51200000ul     // 25.6M  [K2..K5]
#define OF_Y1     76800000ul     // 6.4M   [K1..K2]
#define OF_VW     83200000ul     // 3.2M   [K5..K7]
#define OF_INV    86400000ul     // 262144 ints [Kinv..K10]
#define OF_PRE17  0ul            // 15.36M (reuse y34) [K7..K8]
#define OF_X17    16000000ul     // 15.36M (reuse y34) [K8..K10]
#define OF_Y1819  32000000ul     // 15.36M (reuse y34) y18 then y19 in-place
#define STATS_BYTE 346648576ul   // (86400000+262144)*4, 8B aligned

// stats (double) offsets: layout per layer = sum[C] then sumsq[C]
#define D_ST1 0
#define D_ST2 16
#define D_ST3 80
#define D_ST4 208
#define D_SB1 336
#define D_SB2 592
#define D_S18 656
#define D_S19 912
#define D_TOTAL 1168

__device__ __forceinline__ float mishf(float x) {
  // x * tanh(softplus(x)) == x - 2x/((1+e^x)^2 + 1); robust at +-inf
  float e = __expf(x);
  float u = 1.0f + e;
  return x - 2.0f * x / (u * u + 1.0f);
}

template <int N>
__device__ __forceinline__ void wave_red_sum(float* v) {
#pragma unroll
  for (int d = 1; d < 64; d <<= 1) {
#pragma unroll
    for (int i = 0; i < N; i++) v[i] += __shfl_xor(v[i], d, 64);
  }
}

// ---------------- inverse scatter map ----------------
__global__ void k_inv(const int* __restrict__ coors, int* __restrict__ inv) {
  int n = blockIdx.x * 256 + threadIdx.x;
  if (n < NB_) {
    int h = coors[2 * n], w = coors[2 * n + 1];
    inv[h * W_ + w] = n;
  }
}

// ---------------- K1: y1 = voxels @ W1^T, stats(y1) ----------------
__global__ void k1(const float* __restrict__ vox, const float* __restrict__ W1,
                   float* __restrict__ y1, double* __restrict__ st) {
  __shared__ float wl[64];
  __shared__ float lst[16];
  int t = threadIdx.x;
  if (t < 64) wl[t] = W1[t];
  if (t < 16) lst[t] = 0.f;
  __syncthreads();
  size_t s = (size_t)blockIdx.x * 256 + t;
  const float4* vp = (const float4*)(vox + s * 8);
  float4 a0 = vp[0], a1 = vp[1];
  float x[8] = {a0.x, a0.y, a0.z, a0.w, a1.x, a1.y, a1.z, a1.w};
  float y[8];
#pragma unroll
  for (int o = 0; o < 8; o++) {
    float a = 0.f;
#pragma unroll
    for (int c = 0; c < 8; c++) a += x[c] * wl[o * 8 + c];
    y[o] = a;
  }
  float4* yp = (float4*)(y1 + s * 8);
  yp[0] = make_float4(y[0], y[1], y[2], y[3]);
  yp[1] = make_float4(y[4], y[5], y[6], y[7]);
  float v[16];
#pragma unroll
  for (int i = 0; i < 8; i++) { v[i] = y[i]; v[8 + i] = y[i] * y[i]; }
  wave_red_sum<16>(v);
  if ((t & 63) == 0) {
#pragma unroll
    for (int i = 0; i < 16; i++) atomicAdd(&lst[i], v[i]);
  }
  __syncthreads();
  if (t < 16) atomicAdd(&st[t], (double)lst[t]);
}

// ---------------- K2: p1=act(y1); max_T; y2 = [p1,a] @ W2^T; stats(y2) ------
__global__ void k2(const float* __restrict__ y1, const double* __restrict__ st1,
                   const float* __restrict__ g1, const float* __restrict__ b1,
                   const float* __restrict__ W2, float* __restrict__ y2,
                   double* __restrict__ st2) {
  __shared__ float wl[512];
  __shared__ float ab[8][2];
  __shared__ float lst[64];
  int t = threadIdx.x;
  wl[t] = W2[t];                 // 256 threads: two elements each
  wl[256 + t] = W2[256 + t];
  if (t < 8) {
    double m = st1[t] / (double)NVT_;
    double var = st1[8 + t] / (double)NVT_ - m * m;
    if (var < 0) var = 0;
    float A = (float)((double)g1[t] / sqrt(var + 1e-5));
    ab[t][0] = A; ab[t][1] = b1[t] - (float)m * A;
  }
  if (t < 64) lst[t] = 0.f;
  __syncthreads();
  size_t s = (size_t)blockIdx.x * 256 + t;  // (voxel, ti) = (s/16, s%16)
  const float4* yp = (const float4*)(y1 + s * 8);
  float4 f0 = yp[0], f1 = yp[1];
  float in[8] = {f0.x, f0.y, f0.z, f0.w, f1.x, f1.y, f1.z, f1.w};
  float xr[16];
#pragma unroll
  for (int c = 0; c < 8; c++) xr[c] = mishf(in[c] * ab[c][0] + ab[c][1]);
#pragma unroll
  for (int c = 0; c < 8; c++) xr[8 + c] = xr[c];
#pragma unroll
  for (int d = 1; d < 16; d <<= 1) {
#pragma unroll
    for (int c = 0; c < 8; c++)
      xr[8 + c] = fmaxf(xr[8 + c], __shfl_xor(xr[8 + c], d, 64));
  }
  float yo[32];
#pragma unroll
  for (int o = 0; o < 32; o++) {
    float a = 0.f;
    const float4* wp = (const float4*)(wl + o * 16);
#pragma unroll
    for (int c4 = 0; c4 < 4; c4++) {
      float4 w4 = wp[c4];
      a += xr[c4 * 4 + 0] * w4.x + xr[c4 * 4 + 1] * w4.y +
           xr[c4 * 4 + 2] * w4.z + xr[c4 * 4 + 3] * w4.w;
    }
    yo[o] = a;
  }
  float4* op = (float4*)(y2 + s * 32);
#pragma unroll
  for (int j = 0; j < 8; j++)
    op[j] = make_float4(yo[j * 4], yo[j * 4 + 1], yo[j * 4 + 2], yo[j * 4 + 3]);
#pragma unroll
  for (int ch = 0; ch < 4; ch++) {
    float v[16];
#pragma unroll
    for (int i = 0; i < 8; i++) {
      v[i] = yo[ch * 8 + i]; v[8 + i] = v[i] * v[i];
    }
    wave_red_sum<16>(v);
    if ((t & 63) == 0) {
#pragma unroll
      for (int i = 0; i < 8; i++) {
        atomicAdd(&lst[ch * 8 + i], v[i]);
        atomicAdd(&lst[32 + ch * 8 + i], v[8 + i]);
      }
    }
  }
  __syncthreads();
  if (t < 64) atomicAdd(&st2[t], (double)lst[t]);
}

// ------- K3: x2 = [act(y2),max]*mask (in regs); y3 = x2 @ W3^T; stats(y3) ---
__global__ void k3(const float* __restrict__ y2, const double* __restrict__ st2,
                   const float* __restrict__ g2, const float* __restrict__ b2,
                   const float* __restrict__ vmask, const float* __restrict__ W3,
                   float* __restrict__ y3, double* __restrict__ st3) {
  __shared__ float wl[4096];
  __shared__ float ab[32][2];
  __shared__ float lst[128];
  int t = threadIdx.x;
  for (int i = t; i < 4096; i += 256) wl[i] = W3[i];
  if (t < 32) {
    double m = st2[t] / (double)NVT_;
    double var = st2[32 + t] / (double)NVT_ - m * m;
    if (var < 0) var = 0;
    float A = (float)((double)g2[t] / sqrt(var + 1e-5));
    ab[t][0] = A; ab[t][1] = b2[t] - (float)m * A;
  }
  if (t < 128) lst[t] = 0.f;
  __syncthreads();
  size_t s = (size_t)blockIdx.x * 256 + t;
  float xr[64];
  const float4* yp = (const float4*)(y2 + s * 32);
#pragma unroll
  for (int j = 0; j < 8; j++) {
    float4 f = yp[j];
    xr[j * 4 + 0] = mishf(f.x * ab[j * 4 + 0][0] + ab[j * 4 + 0][1]);
    xr[j * 4 + 1] = mishf(f.y * ab[j * 4 + 1][0] + ab[j * 4 + 1][1]);
    xr[j * 4 + 2] = mishf(f.z * ab[j * 4 + 2][0] + ab[j * 4 + 2][1]);
    xr[j * 4 + 3] = mishf(f.w * ab[j * 4 + 3][0] + ab[j * 4 + 3][1]);
  }
#pragma unroll
  for (int c = 0; c < 32; c++) xr[32 + c] = xr[c];
#pragma unroll
  for (int d = 1; d < 16; d <<= 1) {
#pragma unroll
    for (int c = 0; c < 32; c++)
      xr[32 + c] = fmaxf(xr[32 + c], __shfl_xor(xr[32 + c], d, 64));
  }
  float m = vmask[s];
#pragma unroll
  for (int c = 0; c < 64; c++) xr[c] *= m;
#pragma unroll
  for (int oc = 0; oc < 4; oc++) {
    float yo[16];
#pragma unroll
    for (int o = 0; o < 16; o++) {
      float a = 0.f;
      const float4* wp = (const float4*)(wl + (oc * 16 + o) * 64);
#pragma unroll
      for (int c4 = 0; c4 < 16; c4++) {
        float4 w4 = wp[c4];
        a += xr[c4 * 4 + 0] * w4.x + xr[c4 * 4 + 1] * w4.y +
             xr[c4 * 4 + 2] * w4.z + xr[c4 * 4 + 3] * w4.w;
      }
      yo[o] = a;
    }
    float4* op = (float4*)(y3 + s * 64 + oc * 16);
#pragma unroll
    for (int j = 0; j < 4; j++)
      op[j] = make_float4(yo[j * 4], yo[j * 4 + 1], yo[j * 4 + 2], yo[j * 4 + 3]);
    float v[32];
#pragma unroll
    for (int i = 0; i < 16; i++) { v[i] = yo[i]; v[16 + i] = yo[i] * yo[i]; }
    wave_red_sum<32>(v);
    if ((t & 63) == 0) {
#pragma unroll
      for (int i = 0; i < 16; i++) {
        atomicAdd(&lst[oc * 16 + i], v[i]);
        atomicAdd(&lst[64 + oc * 16 + i], v[16 + i]);
      }
    }
  }
  __syncthreads();
  if (t < 128) atomicAdd(&st3[t], (double)lst[t]);
}

// ---------------- K4: x3=act(y3); y4 = x3 @ W4^T (in-place); stats(y4) ------
__global__ void k4(float* y34, const double* __restrict__ st3,
                   const float* __restrict__ g3, const float* __restrict__ b3,
                   const float* __restrict__ W4, double* __restrict__ st4) {
  __shared__ float wl[4096];
  __shared__ float ab[64][2];
  __shared__ float lst[128];
  int t = threadIdx.x;
  for (int i = t; i < 4096; i += 256) wl[i] = W4[i];
  if (t < 64) {
    double m = st3[t] / (double)NVT_;
    double var = st3[64 + t] / (double)NVT_ - m * m;
    if (var < 0) var = 0;
    float A = (float)((double)g3[t] / sqrt(var + 1e-5));
    ab[t][0] = A; ab[t][1] = b3[t] - (float)m * A;
  }
  if (t < 128) lst[t] = 0.f;
  __syncthreads();
  size_t s = (size_t)blockIdx.x * 256 + t;
  float xr[64];
  const float4* yp = (const float4*)(y34 + s * 64);
#pragma unroll
  for (int j = 0; j < 16; j++) {
    float4 f = yp[j];
    xr[j * 4 + 0] = mishf(f.x * ab[j * 4 + 0][0] + ab[j * 4 + 0][1]);
    xr[j * 4 + 1] = mishf(f.y * ab[j * 4 + 1][0] + ab[j * 4 + 1][1]);
    xr[j * 4 + 2] = mishf(f.z * ab[j * 4 + 2][0] + ab[j * 4 + 2][1]);
    xr[j * 4 + 3] = mishf(f.w * ab[j * 4 + 3][0] + ab[j * 4 + 3][1]);
  }
#pragma unroll
  for (int oc = 0; oc < 4; oc++) {
    float yo[16];
#pragma unroll
    for (int o = 0; o < 16; o++) {
      float a = 0.f;
      const float4* wp = (const float4*)(wl + (oc * 16 + o) * 64);
#pragma unroll
      for (int c4 = 0; c4 < 16; c4++) {
        float4 w4 = wp[c4];
        a += xr[c4 * 4 + 0] * w4.x + xr[c4 * 4 + 1] * w4.y +
             xr[c4 * 4 + 2] * w4.z + xr[c4 * 4 + 3] * w4.w;
      }
      yo[o] = a;
    }
    float4* op = (float4*)(y34 + s * 64 + oc * 16);
#pragma unroll
    for (int j = 0; j < 4; j++)
      op[j] = make_float4(yo[j * 4], yo[j * 4 + 1], yo[j * 4 + 2], yo[j * 4 + 3]);
    float v[32];
#pragma unroll
    for (int i = 0; i < 16; i++) { v[i] = yo[i]; v[16 + i] = yo[i] * yo[i]; }
    wave_red_sum<32>(v);
    if ((t & 63) == 0) {
#pragma unroll
      for (int i = 0; i < 16; i++) {
        atomicAdd(&lst[oc * 16 + i], v[i]);
        atomicAdd(&lst[64 + oc * 16 + i], v[16 + i]);
      }
    }
  }
  __syncthreads();
  if (t < 128) atomicAdd(&st4[t], (double)lst[t]);
}

// --- K5: recompute x2 from y2; x4=act(y4)*mask+x2; voxelwise = max_T -------
__global__ void k5(const float* __restrict__ y34, const double* __restrict__ st4,
                   const float* __restrict__ g4, const float* __restrict__ b4,
                   const float* __restrict__ y2, const double* __restrict__ st2,
                   const float* __restrict__ g2, const float* __restrict__ b2,
                   const float* __restrict__ vmask, float* __restrict__ vw) {
  __shared__ float ab4[64][2];
  __shared__ float ab2[32][2];
  int t = threadIdx.x;
  if (t < 64) {
    double m = st4[t] / (double)NVT_;
    double var = st4[64 + t] / (double)NVT_ - m * m;
    if (var < 0) var = 0;
    float A = (float)((double)g4[t] / sqrt(var + 1e-5));
    ab4[t][0] = A; ab4[t][1] = b4[t] - (float)m * A;
  } else if (t >= 128 && t < 160) {
    int c = t - 128;
    double m = st2[c] / (double)NVT_;
    double var = st2[32 + c] / (double)NVT_ - m * m;
    if (var < 0) var = 0;
    float A = (float)((double)g2[c] / sqrt(var + 1e-5));
    ab2[c][0] = A; ab2[c][1] = b2[c] - (float)m * A;
  }
  __syncthreads();
  size_t s = (size_t)blockIdx.x * 256 + t;
  int v = (int)(s >> 4), ti = t & 15;
  float msk = vmask[s];
  // x2 = [act2(y2), max_T act2(y2)] * msk  (max taken pre-mask, as reference)
  float xr[64];
  const float4* y2p = (const float4*)(y2 + s * 32);
#pragma unroll
  for (int j = 0; j < 8; j++) {
    float4 f = y2p[j];
    xr[j * 4 + 0] = mishf(f.x * ab2[j * 4 + 0][0] + ab2[j * 4 + 0][1]);
    xr[j * 4 + 1] = mishf(f.y * ab2[j * 4 + 1][0] + ab2[j * 4 + 1][1]);
    xr[j * 4 + 2] = mishf(f.z * ab2[j * 4 + 2][0] + ab2[j * 4 + 2][1]);
    xr[j * 4 + 3] = mishf(f.w * ab2[j * 4 + 3][0] + ab2[j * 4 + 3][1]);
  }
#pragma unroll
  for (int c = 0; c < 32; c++) xr[32 + c] = xr[c];
#pragma unroll
  for (int d = 1; d < 16; d <<= 1) {
#pragma unroll
    for (int c = 0; c < 32; c++)
      xr[32 + c] = fmaxf(xr[32 + c], __shfl_xor(xr[32 + c], d, 64));
  }
#pragma unroll
  for (int c = 0; c < 64; c++) xr[c] *= msk;
  // x4 = act4(y4)*msk + x2
  const float4* yp = (const float4*)(y34 + s * 64);
#pragma unroll
  for (int j = 0; j < 16; j++) {
    float4 f = yp[j];
    xr[j * 4 + 0] += mishf(f.x * ab4[j * 4 + 0][0] + ab4[j * 4 + 0][1]) * msk;
    xr[j * 4 + 1] += mishf(f.y * ab4[j * 4 + 1][0] + ab4[j * 4 + 1][1]) * msk;
    xr[j * 4 + 2] += mishf(f.z * ab4[j * 4 + 2][0] + ab4[j * 4 + 2][1]) * msk;
    xr[j * 4 + 3] += mishf(f.w * ab4[j * 4 + 3][0] + ab4[j * 4 + 3][1]) * msk;
  }
#pragma unroll
  for (int d = 1; d < 16; d <<= 1) {
#pragma unroll
    for (int c = 0; c < 64; c++)
      xr[c] = fmaxf(xr[c], __shfl_xor(xr[c], d, 64));
  }
  *(float4*)(vw + (size_t)v * 64 + ti * 4) =
      make_float4(xr[ti * 4], xr[ti * 4 + 1], xr[ti * 4 + 2], xr[ti * 4 + 3]);
}

// ---------------- K6: stats of grouped einsum-1 output (no materialize) -----
__global__ void k6(const float* __restrict__ vw, const int* __restrict__ idx,
                   const float* __restrict__ Wb1, double* __restrict__ sb1) {
  __shared__ float wl[1024];   // wl[(q*8+p)*16 + g]
  __shared__ float lst[256];
  int t = threadIdx.x;
  for (int i = t; i < 1024; i += 256) {
    int g = i >> 6, qp = i & 63;
    wl[qp * 16 + g] = Wb1[i];
  }
  lst[t] = 0.f;
  __syncthreads();
  int g = t & 15, nl = t >> 4;
  float ss[8] = {0, 0, 0, 0, 0, 0, 0, 0}, sq[8] = {0, 0, 0, 0, 0, 0, 0, 0};
  for (int it = 0; it < 16; ++it) {
    int n = blockIdx.x * 256 + it * 16 + nl;
    if (n < NB_) {
      int id[8];
#pragma unroll
      for (int p = 0; p < 8; p++) id[p] = idx[n * 8 + p];
      float xg[4][8];
#pragma unroll
      for (int p = 0; p < 8; p++) {
        float4 f = *(const float4*)(vw + (size_t)id[p] * 64 + g * 4);
        xg[0][p] = f.x; xg[1][p] = f.y; xg[2][p] = f.z; xg[3][p] = f.w;
      }
#pragma unroll
      for (int q = 0; q < 8; q++) {
        float wq[8];
#pragma unroll
        for (int p = 0; p < 8; p++) wq[p] = wl[(q * 8 + p) * 16 + g];
#pragma unroll
        for (int c = 0; c < 4; c++) {
          float a = 0.f;
#pragma unroll
          for (int p = 0; p < 8; p++) a += xg[c][p] * wq[p];
          ss[q] += a; sq[q] += a * a;
        }
      }
    }
  }
#pragma unroll
  for (int d = 16; d < 64; d <<= 1) {
#pragma unroll
    for (int q = 0; q < 8; q++) {
      ss[q] += __shfl_xor(ss[q], d, 64);
      sq[q] += __shfl_xor(sq[q], d, 64);
    }
  }
  if ((t & 48) == 0) {
#pragma unroll
    for (int q = 0; q < 8; q++) {
      atomicAdd(&lst[g * 8 + q], ss[q]);
      atomicAdd(&lst[128 + g * 8 + q], sq[q]);
    }
  }
  __syncthreads();
  atomicAdd(&sb1[t], (double)lst[t]);
}

// ------- K7: recompute einsum1, act, bevmask, einsum2 -> pre17; stats -------
__global__ void k7(const float* __restrict__ vw, const int* __restrict__ idx,
                   const float* __restrict__ Wb1, const double* __restrict__ sb1,
                   const float* __restrict__ gb1, const float* __restrict__ bb1,
                   const float* __restrict__ bmask, const float* __restrict__ Wb2,
                   float* __restrict__ pre17, double* __restrict__ sb2) {
  __shared__ float wl[1024];
  __shared__ float w2l[256];   // w2l[(q2*8+q)*16 + g]
  __shared__ float ab[128][2];
  __shared__ float lst[64];
  int t = threadIdx.x;
  for (int i = t; i < 1024; i += 256) {
    int g = i >> 6, qp = i & 63;
    wl[qp * 16 + g] = Wb1[i];
  }
  {
    int g = t >> 4, qq = t & 15;
    w2l[qq * 16 + g] = Wb2[t];
  }
  if (t < 128) {
    double m = sb1[t] / 480000.0;
    double var = sb1[128 + t] / 480000.0 - m * m;
    if (var < 0) var = 0;
    float A = (float)((double)gb1[t] / sqrt(var + 1e-5));
    ab[t][0] = A; ab[t][1] = bb1[t] - (float)m * A;
  }
  if (t < 64) lst[t] = 0.f;
  __syncthreads();
  int g = t & 15, nl = t >> 4;
  float s2[2] = {0, 0}, q2s[2] = {0, 0};
  for (int it = 0; it < 16; ++it) {
    int n = blockIdx.x * 256 + it * 16 + nl;
    if (n < NB_) {
      int id[8];
      float bmv[8];
#pragma unroll
      for (int p = 0; p < 8; p++) { id[p] = idx[n * 8 + p]; bmv[p] = bmask[n * 8 + p]; }
      float xg[4][8];
#pragma unroll
      for (int p = 0; p < 8; p++) {
        float4 f = *(const float4*)(vw + (size_t)id[p] * 64 + g * 4);
        xg[0][p] = f.x; xg[1][p] = f.y; xg[2][p] = f.z; xg[3][p] = f.w;
      }
      float th[4][8];
#pragma unroll
      for (int q = 0; q < 8; q++) {
        float wq[8];
#pragma unroll
        for (int p = 0; p < 8; p++) wq[p] = wl[(q * 8 + p) * 16 + g];
        float A = ab[g * 8 + q][0], B = ab[g * 8 + q][1];
#pragma unroll
        for (int c = 0; c < 4; c++) {
          float a = 0.f;
#pragma unroll
          for (int p = 0; p < 8; p++) a += xg[c][p] * wq[p];
          th[c][q] = mishf(a * A + B) * bmv[q];
        }
      }
#pragma unroll
      for (int c = 0; c < 4; c++) {
        float v0 = 0.f, v1 = 0.f;
#pragma unroll
        for (int q = 0; q < 8; q++) {
          v0 += th[c][q] * w2l[q * 16 + g];
          v1 += th[c][q] * w2l[(8 + q) * 16 + g];
        }
        *(float2*)(pre17 + (size_t)n * 128 + c * 32 + g * 2) = make_float2(v0, v1);
        s2[0] += v0; q2s[0] += v0 * v0;
        s2[1] += v1; q2s[1] += v1 * v1;
      }
    }
  }
#pragma unroll
  for (int d = 16; d < 64; d <<= 1) {
#pragma unroll
    for (int j = 0; j < 2; j++) {
      s2[j] += __shfl_xor(s2[j], d, 64);
      q2s[j] += __shfl_xor(q2s[j], d, 64);
    }
  }
  if ((t & 48) == 0) {
#pragma unroll
    for (int j = 0; j < 2; j++) {
      atomicAdd(&lst[g * 2 + j], s2[j]);
      atomicAdd(&lst[32 + g * 2 + j], q2s[j]);
    }
  }
  __syncthreads();
  if (t < 64) atomicAdd(&sb2[t], (double)lst[t]);
}

// -------- K8/K9: 128x128 GEMM with fused input act (tiled in LDS) ----------
// MODE 0: in = pre17 (x17 order), act via ab[32] (bfe2 BN), write x17, out y18
// MODE 1: in = y18, act via ab[128] (bfe3 BN), out y19 (in-place safe)
template <int MODE>
__global__ void kgemm(const float* xin, const double* __restrict__ stin,
                      const float* __restrict__ gam, const float* __restrict__ bet,
                      const float* __restrict__ Wt, float* xact_out,
                      float* yout, double* __restrict__ stout) {
  __shared__ float xs[32 * 129];
  __shared__ float wsh[128 * 33];
  __shared__ float ab[128][2];
  __shared__ float lst[256];
  int t = threadIdx.x;
  const int nch = (MODE == 0) ? 32 : 128;
  const double den = (MODE == 0) ? 480000.0 : 120000.0;
  if (t < nch) {
    double m = stin[t] / den;
    double var = stin[nch + t] / den - m * m;
    if (var < 0) var = 0;
    float A = (float)((double)gam[t] / sqrt(var + 1e-5));
    ab[t][0] = A; ab[t][1] = bet[t] - (float)m * A;
  }
  lst[t] = 0.f;
  __syncthreads();
  int s0 = blockIdx.x * 128;
  int oc = t & 7, sc = t >> 3;
  int cl = t & 31, sl8 = t >> 5;
  float acc[64];
#pragma unroll
  for (int i = 0; i < 64; i++) acc[i] = 0.f;
  for (int cb = 0; cb < 128; cb += 32) {
#pragma unroll
    for (int r = 0; r < 16; r++) {
      int slocal = r * 8 + sl8;
      int sg = s0 + slocal;
      float v = 0.f;
      if (sg < NB_) {
        float h = xin[(size_t)sg * 128 + cb + cl];
        if (MODE == 0) {
          v = mishf(h * ab[cl][0] + ab[cl][1]);
          xact_out[(size_t)sg * 128 + cb + cl] = v;
        } else {
          v = mishf(h * ab[cb + cl][0] + ab[cb + cl][1]);
        }
      }
      xs[cl * 129 + slocal] = v;
    }
#pragma unroll
    for (int r = 0; r < 16; r++) {
      int o = r * 8 + sl8;
      wsh[o * 33 + cl] = Wt[o * 128 + cb + cl];
    }
    __syncthreads();
#pragma unroll 4
    for (int c = 0; c < 32; c++) {
      float xv[4];
#pragma unroll
      for (int i = 0; i < 4; i++) xv[i] = xs[c * 129 + sc * 4 + i];
#pragma unroll
      for (int k = 0; k < 16; k++) {
        float wv = wsh[(k * 8 + oc) * 33 + c];
#pragma unroll
        for (int i = 0; i < 4; i++) acc[k * 4 + i] += wv * xv[i];
      }
    }
    __syncthreads();
  }
  float ssum[16], ssq[16];
#pragma unroll
  for (int k = 0; k < 16; k++) { ssum[k] = 0.f; ssq[k] = 0.f; }
#pragma unroll
  for (int i = 0; i < 4; i++) {
    int sg = s0 + sc * 4 + i;
    if (sg < NB_) {
#pragma unroll
      for (int k = 0; k < 16; k++) {
        float v = acc[k * 4 + i];
        yout[(size_t)sg * 128 + k * 8 + oc] = v;
        ssum[k] += v; ssq[k] += v * v;
      }
    }
  }
#pragma unroll
  for (int d = 8; d < 64; d <<= 1) {
#pragma unroll
    for (int k = 0; k < 16; k++) {
      ssum[k] += __shfl_xor(ssum[k], d, 64);
      ssq[k] += __shfl_xor(ssq[k], d, 64);
    }
  }
  if ((t & 63) < 8) {
#pragma unroll
    for (int k = 0; k < 16; k++) {
      atomicAdd(&lst[k * 8 + oc], ssum[k]);
      atomicAdd(&lst[128 + k * 8 + oc], ssq[k]);
    }
  }
  __syncthreads();
  atomicAdd(&stout[t], (double)lst[t]);
}

// ------- K10: x19 = act(y19)+x17, transposed coalesced write of output ------
__global__ void k10(const float* __restrict__ y19, const float* __restrict__ x17,
                    const double* __restrict__ s19, const float* __restrict__ g3,
                    const float* __restrict__ b3, const int* __restrict__ inv,
                    float* __restrict__ out) {
  __shared__ float buf[256 * 32];
  __shared__ float ab[32][2];
  int t = threadIdx.x;
  int w = blockIdx.x, hh = blockIdx.y, ch = blockIdx.z;
  if (t < 32) {
    int c = ch * 32 + t;
    double m = s19[c] / 120000.0;
    double var = s19[128 + c] / 120000.0 - m * m;
    if (var < 0) var = 0;
    float A = (float)((double)g3[c] / sqrt(var + 1e-5));
    ab[t][0] = A; ab[t][1] = b3[c] - (float)m * A;
  }
  __syncthreads();
  int lane = t & 31, rg = t >> 5;
#pragma unroll 4
  for (int r = 0; r < 32; r++) {
    int h_l = r * 8 + rg;
    int h = hh * 256 + h_l;
    int n = inv[h * W_ + w];
    float v = 0.f;
    if (n >= 0) {
      float y = y19[(size_t)n * 128 + ch * 32 + lane];
      v = mishf(y * ab[lane][0] + ab[lane][1]) +
          x17[(size_t)n * 128 + ch * 32 + lane];
    }
    buf[h_l * 32 + (lane ^ (h_l & 31))] = v;
  }
  __syncthreads();
#pragma unroll 4
  for (int c_l = 0; c_l < 32; c_l++) {
    out[(size_t)(ch * 32 + c_l) * (W_ * H_) + (size_t)w * H_ + hh * 256 + t] =
        buf[t * 32 + (c_l ^ (t & 31))];
  }
}

extern "C" void kernel_launch(void* const* d_in, const int* in_sizes, int n_in,
                              void* d_out, int out_size, void* d_ws, size_t ws_size,
                              hipStream_t stream) {
  const float* voxels = (const float*)d_in[0];
  const float* vmask = (const float*)d_in[1];
  const float* bmask = (const float*)d_in[2];
  const float* W1 = (const float*)d_in[3];
  const float* g1 = (const float*)d_in[4];
  const float* b1 = (const float*)d_in[5];
  const float* W2 = (const float*)d_in[6];
  const float* g2 = (const float*)d_in[7];
  const float* b2 = (const float*)d_in[8];
  const float* W3 = (const float*)d_in[9];
  const float* g3 = (const float*)d_in[10];
  const float* b3 = (const float*)d_in[11];
  const float* W4 = (const float*)d_in[12];
  const float* g4 = (const float*)d_in[13];
  const float* b4 = (const float*)d_in[14];
  const float* Wb1 = (const float*)d_in[15];
  const float* gb1 = (const float*)d_in[16];
  const float* bb1 = (const float*)d_in[17];
  const float* Wb2 = (const float*)d_in[18];
  const float* gb2 = (const float*)d_in[19];
  const float* bb2 = (const float*)d_in[20];
  const float* Wb3 = (const float*)d_in[21];
  const float* gb3 = (const float*)d_in[22];
  const float* bb3 = (const float*)d_in[23];
  const int* bevsidx = (const int*)d_in[24];
  const int* bevcoors = (const int*)d_in[25];

  float* ws = (float*)d_ws;
  float* y1 = ws + OF_Y1;
  float* y2 = ws + OF_Y2;
  float* y34 = ws + OF_Y34;
  float* vw = ws + OF_VW;
  float* pre17 = ws + OF_PRE17;
  float* x17 = ws + OF_X17;
  float* y1819 = ws + OF_Y1819;
  int* inv = (int*)(ws + OF_INV);
  double* stats = (double*)((char*)d_ws + STATS_BYTE);

  hipMemsetAsync(stats, 0, D_TOTAL * sizeof(double), stream);
  hipMemsetAsync(inv, 0xFF, (size_t)(H_ * W_) * sizeof(int), stream);

  k_inv<<<469, 256, 0, stream>>>(bevcoors, inv);
  k1<<<3125, 256, 0, stream>>>(voxels, W1, y1, stats + D_ST1);
  k2<<<3125, 256, 0, stream>>>(y1, stats + D_ST1, g1, b1, W2, y2, stats + D_ST2);
  k3<<<3125, 256, 0, stream>>>(y2, stats + D_ST2, g2, b2, vmask, W3, y34,
                               stats + D_ST3);
  k4<<<3125, 256, 0, stream>>>(y34, stats + D_ST3, g3, b3, W4, stats + D_ST4);
  k5<<<3125, 256, 0, stream>>>(y34, stats + D_ST4, g4, b4, y2, stats + D_ST2,
                               g2, b2, vmask, vw);
  k6<<<469, 256, 0, stream>>>(vw, bevsidx, Wb1, stats + D_SB1);
  k7<<<469, 256, 0, stream>>>(vw, bevsidx, Wb1, stats + D_SB1, gb1, bb1, bmask,
                              Wb2, pre17, stats + D_SB2);
  kgemm<0><<<938, 256, 0, stream>>>(pre17, stats + D_SB2, gb2, bb2, Wb3, x17,
                                    y1819, stats + D_S18);
  kgemm<1><<<938, 256, 0, stream>>>(y1819, stats + D_S18, gb3, bb3, Wb3, nullptr,
                                    y1819, stats + D_S19);
  dim3 g10(512, 2, 4);
  k10<<<g10, 256, 0, stream>>>(y1819, x17, stats + D_S19, gb3, bb3, inv,
                               (float*)d_out);
}

// Round 6
// 3176.953 us; speedup vs baseline: 1.5109x; 1.5109x over previous
//
#include <hip/hip_runtime.h>
#include <math.h>

#define NV_   50000
#define T16_  16
#define NVT_  800000
#define NB_   120000
#define G_    16
#define P_    8
#define H_    512
#define W_    512

// ---- workspace layout (float element offsets) ----
// y34 region (51.2M floats) is reused after K5 for pre17/x17/y1819.
#define OF_Y34    0ul            // 51.2M  y3 then y4 in-place [K3..K5]
#define OF_Y2     51200000ul     // 25.6M  [K2..K5]
#define OF_Y1     76800000ul     // 6.4M   [K1..K2]
#define OF_VW     83200000ul     // 3.2M   [K5..K7]
#define OF_INV    86400000ul     // 262144 ints [Kinv..K10]
#define OF_PRE17  0ul            // 15.36M (reuse y34) [K7..K8]
#define OF_X17    16000000ul     // 15.36M (reuse y34) [K8..K10]
#define OF_Y1819  32000000ul     // 15.36M (reuse y34) y18 then y19 in-place
#define STATS_BYTE 346648576ul   // (86400000+262144)*4, 8B aligned

// stats (double) offsets: layout per layer = sum[C] then sumsq[C]
#define D_ST1 0
#define D_ST2 16
#define D_ST3 80
#define D_ST4 208
#define D_SB1 336
#define D_SB2 592
#define D_S18 656
#define D_S19 912
#define D_TOTAL 1168

// VGPR-cap control: 2 waves/EU -> ~256 VGPRs (no spill for xr[64]-style kernels)
#define LB_HEAVY __launch_bounds__(256, 2)
#define LB_LIGHT __launch_bounds__(256, 4)

__device__ __forceinline__ float mishf(float x) {
  // x * tanh(softplus(x)) == x - 2x/((1+e^x)^2 + 1); robust at +-inf
  float e = __expf(x);
  float u = 1.0f + e;
  return x - 2.0f * x / (u * u + 1.0f);
}

template <int N>
__device__ __forceinline__ void wave_red_sum(float* v) {
#pragma unroll
  for (int d = 1; d < 64; d <<= 1) {
#pragma unroll
    for (int i = 0; i < N; i++) v[i] += __shfl_xor(v[i], d, 64);
  }
}

// ---------------- inverse scatter map ----------------
__global__ void LB_LIGHT k_inv(const int* __restrict__ coors, int* __restrict__ inv) {
  int n = blockIdx.x * 256 + threadIdx.x;
  if (n < NB_) {
    int h = coors[2 * n], w = coors[2 * n + 1];
    inv[h * W_ + w] = n;
  }
}

// ---------------- K1: y1 = voxels @ W1^T, stats(y1) ----------------
__global__ void LB_LIGHT k1(const float* __restrict__ vox, const float* __restrict__ W1,
                   float* __restrict__ y1, double* __restrict__ st) {
  __shared__ float wl[64];
  __shared__ float lst[16];
  int t = threadIdx.x;
  if (t < 64) wl[t] = W1[t];
  if (t < 16) lst[t] = 0.f;
  __syncthreads();
  size_t s = (size_t)blockIdx.x * 256 + t;
  const float4* vp = (const float4*)(vox + s * 8);
  float4 a0 = vp[0], a1 = vp[1];
  float x[8] = {a0.x, a0.y, a0.z, a0.w, a1.x, a1.y, a1.z, a1.w};
  float y[8];
#pragma unroll
  for (int o = 0; o < 8; o++) {
    float a = 0.f;
#pragma unroll
    for (int c = 0; c < 8; c++) a += x[c] * wl[o * 8 + c];
    y[o] = a;
  }
  float4* yp = (float4*)(y1 + s * 8);
  yp[0] = make_float4(y[0], y[1], y[2], y[3]);
  yp[1] = make_float4(y[4], y[5], y[6], y[7]);
  float v[16];
#pragma unroll
  for (int i = 0; i < 8; i++) { v[i] = y[i]; v[8 + i] = y[i] * y[i]; }
  wave_red_sum<16>(v);
  if ((t & 63) == 0) {
#pragma unroll
    for (int i = 0; i < 16; i++) atomicAdd(&lst[i], v[i]);
  }
  __syncthreads();
  if (t < 16) atomicAdd(&st[t], (double)lst[t]);
}

// ---------------- K2: p1=act(y1); max_T; y2 = [p1,a] @ W2^T; stats(y2) ------
__global__ void LB_HEAVY k2(const float* __restrict__ y1, const double* __restrict__ st1,
                   const float* __restrict__ g1, const float* __restrict__ b1,
                   const float* __restrict__ W2, float* __restrict__ y2,
                   double* __restrict__ st2) {
  __shared__ float wl[512];
  __shared__ float ab[8][2];
  __shared__ float lst[64];
  int t = threadIdx.x;
  wl[t] = W2[t];                 // 256 threads: two elements each
  wl[256 + t] = W2[256 + t];
  if (t < 8) {
    double m = st1[t] / (double)NVT_;
    double var = st1[8 + t] / (double)NVT_ - m * m;
    if (var < 0) var = 0;
    float A = (float)((double)g1[t] / sqrt(var + 1e-5));
    ab[t][0] = A; ab[t][1] = b1[t] - (float)m * A;
  }
  if (t < 64) lst[t] = 0.f;
  __syncthreads();
  size_t s = (size_t)blockIdx.x * 256 + t;  // (voxel, ti) = (s/16, s%16)
  const float4* yp = (const float4*)(y1 + s * 8);
  float4 f0 = yp[0], f1 = yp[1];
  float in[8] = {f0.x, f0.y, f0.z, f0.w, f1.x, f1.y, f1.z, f1.w};
  float xr[16];
#pragma unroll
  for (int c = 0; c < 8; c++) xr[c] = mishf(in[c] * ab[c][0] + ab[c][1]);
#pragma unroll
  for (int c = 0; c < 8; c++) xr[8 + c] = xr[c];
#pragma unroll
  for (int d = 1; d < 16; d <<= 1) {
#pragma unroll
    for (int c = 0; c < 8; c++)
      xr[8 + c] = fmaxf(xr[8 + c], __shfl_xor(xr[8 + c], d, 64));
  }
  float yo[32];
#pragma unroll
  for (int o = 0; o < 32; o++) {
    float a = 0.f;
    const float4* wp = (const float4*)(wl + o * 16);
#pragma unroll
    for (int c4 = 0; c4 < 4; c4++) {
      float4 w4 = wp[c4];
      a += xr[c4 * 4 + 0] * w4.x + xr[c4 * 4 + 1] * w4.y +
           xr[c4 * 4 + 2] * w4.z + xr[c4 * 4 + 3] * w4.w;
    }
    yo[o] = a;
  }
  float4* op = (float4*)(y2 + s * 32);
#pragma unroll
  for (int j = 0; j < 8; j++)
    op[j] = make_float4(yo[j * 4], yo[j * 4 + 1], yo[j * 4 + 2], yo[j * 4 + 3]);
#pragma unroll
  for (int ch = 0; ch < 4; ch++) {
    float v[16];
#pragma unroll
    for (int i = 0; i < 8; i++) {
      v[i] = yo[ch * 8 + i]; v[8 + i] = v[i] * v[i];
    }
    wave_red_sum<16>(v);
    if ((t & 63) == 0) {
#pragma unroll
      for (int i = 0; i < 8; i++) {
        atomicAdd(&lst[ch * 8 + i], v[i]);
        atomicAdd(&lst[32 + ch * 8 + i], v[8 + i]);
      }
    }
  }
  __syncthreads();
  if (t < 64) atomicAdd(&st2[t], (double)lst[t]);
}

// ------- K3: x2 = [act(y2),max]*mask (in regs); y3 = x2 @ W3^T; stats(y3) ---
__global__ void LB_HEAVY k3(const float* __restrict__ y2, const double* __restrict__ st2,
                   const float* __restrict__ g2, const float* __restrict__ b2,
                   const float* __restrict__ vmask, const float* __restrict__ W3,
                   float* __restrict__ y3, double* __restrict__ st3) {
  __shared__ float wl[4096];
  __shared__ float ab[32][2];
  __shared__ float lst[128];
  int t = threadIdx.x;
  for (int i = t; i < 4096; i += 256) wl[i] = W3[i];
  if (t < 32) {
    double m = st2[t] / (double)NVT_;
    double var = st2[32 + t] / (double)NVT_ - m * m;
    if (var < 0) var = 0;
    float A = (float)((double)g2[t] / sqrt(var + 1e-5));
    ab[t][0] = A; ab[t][1] = b2[t] - (float)m * A;
  }
  if (t < 128) lst[t] = 0.f;
  __syncthreads();
  size_t s = (size_t)blockIdx.x * 256 + t;
  float xr[64];
  const float4* yp = (const float4*)(y2 + s * 32);
#pragma unroll
  for (int j = 0; j < 8; j++) {
    float4 f = yp[j];
    xr[j * 4 + 0] = mishf(f.x * ab[j * 4 + 0][0] + ab[j * 4 + 0][1]);
    xr[j * 4 + 1] = mishf(f.y * ab[j * 4 + 1][0] + ab[j * 4 + 1][1]);
    xr[j * 4 + 2] = mishf(f.z * ab[j * 4 + 2][0] + ab[j * 4 + 2][1]);
    xr[j * 4 + 3] = mishf(f.w * ab[j * 4 + 3][0] + ab[j * 4 + 3][1]);
  }
#pragma unroll
  for (int c = 0; c < 32; c++) xr[32 + c] = xr[c];
#pragma unroll
  for (int d = 1; d < 16; d <<= 1) {
#pragma unroll
    for (int c = 0; c < 32; c++)
      xr[32 + c] = fmaxf(xr[32 + c], __shfl_xor(xr[32 + c], d, 64));
  }
  float m = vmask[s];
#pragma unroll
  for (int c = 0; c < 64; c++) xr[c] *= m;
#pragma unroll
  for (int oc = 0; oc < 4; oc++) {
    float yo[16];
#pragma unroll
    for (int o = 0; o < 16; o++) {
      float a = 0.f;
      const float4* wp = (const float4*)(wl + (oc * 16 + o) * 64);
#pragma unroll
      for (int c4 = 0; c4 < 16; c4++) {
        float4 w4 = wp[c4];
        a += xr[c4 * 4 + 0] * w4.x + xr[c4 * 4 + 1] * w4.y +
             xr[c4 * 4 + 2] * w4.z + xr[c4 * 4 + 3] * w4.w;
      }
      yo[o] = a;
    }
    float4* op = (float4*)(y3 + s * 64 + oc * 16);
#pragma unroll
    for (int j = 0; j < 4; j++)
      op[j] = make_float4(yo[j * 4], yo[j * 4 + 1], yo[j * 4 + 2], yo[j * 4 + 3]);
    float v[32];
#pragma unroll
    for (int i = 0; i < 16; i++) { v[i] = yo[i]; v[16 + i] = yo[i] * yo[i]; }
    wave_red_sum<32>(v);
    if ((t & 63) == 0) {
#pragma unroll
      for (int i = 0; i < 16; i++) {
        atomicAdd(&lst[oc * 16 + i], v[i]);
        atomicAdd(&lst[64 + oc * 16 + i], v[16 + i]);
      }
    }
  }
  __syncthreads();
  if (t < 128) atomicAdd(&st3[t], (double)lst[t]);
}

// ---------------- K4: x3=act(y3); y4 = x3 @ W4^T (in-place); stats(y4) ------
__global__ void LB_HEAVY k4(float* y34, const double* __restrict__ st3,
                   const float* __restrict__ g3, const float* __restrict__ b3,
                   const float* __restrict__ W4, double* __restrict__ st4) {
  __shared__ float wl[4096];
  __shared__ float ab[64][2];
  __shared__ float lst[128];
  int t = threadIdx.x;
  for (int i = t; i < 4096; i += 256) wl[i] = W4[i];
  if (t < 64) {
    double m = st3[t] / (double)NVT_;
    double var = st3[64 + t] / (double)NVT_ - m * m;
    if (var < 0) var = 0;
    float A = (float)((double)g3[t] / sqrt(var + 1e-5));
    ab[t][0] = A; ab[t][1] = b3[t] - (float)m * A;
  }
  if (t < 128) lst[t] = 0.f;
  __syncthreads();
  size_t s = (size_t)blockIdx.x * 256 + t;
  float xr[64];
  const float4* yp = (const float4*)(y34 + s * 64);
#pragma unroll
  for (int j = 0; j < 16; j++) {
    float4 f = yp[j];
    xr[j * 4 + 0] = mishf(f.x * ab[j * 4 + 0][0] + ab[j * 4 + 0][1]);
    xr[j * 4 + 1] = mishf(f.y * ab[j * 4 + 1][0] + ab[j * 4 + 1][1]);
    xr[j * 4 + 2] = mishf(f.z * ab[j * 4 + 2][0] + ab[j * 4 + 2][1]);
    xr[j * 4 + 3] = mishf(f.w * ab[j * 4 + 3][0] + ab[j * 4 + 3][1]);
  }
#pragma unroll
  for (int oc = 0; oc < 4; oc++) {
    float yo[16];
#pragma unroll
    for (int o = 0; o < 16; o++) {
      float a = 0.f;
      const float4* wp = (const float4*)(wl + (oc * 16 + o) * 64);
#pragma unroll
      for (int c4 = 0; c4 < 16; c4++) {
        float4 w4 = wp[c4];
        a += xr[c4 * 4 + 0] * w4.x + xr[c4 * 4 + 1] * w4.y +
             xr[c4 * 4 + 2] * w4.z + xr[c4 * 4 + 3] * w4.w;
      }
      yo[o] = a;
    }
    float4* op = (float4*)(y34 + s * 64 + oc * 16);
#pragma unroll
    for (int j = 0; j < 4; j++)
      op[j] = make_float4(yo[j * 4], yo[j * 4 + 1], yo[j * 4 + 2], yo[j * 4 + 3]);
    float v[32];
#pragma unroll
    for (int i = 0; i < 16; i++) { v[i] = yo[i]; v[16 + i] = yo[i] * yo[i]; }
    wave_red_sum<32>(v);
    if ((t & 63) == 0) {
#pragma unroll
      for (int i = 0; i < 16; i++) {
        atomicAdd(&lst[oc * 16 + i], v[i]);
        atomicAdd(&lst[64 + oc * 16 + i], v[16 + i]);
      }
    }
  }
  __syncthreads();
  if (t < 128) atomicAdd(&st4[t], (double)lst[t]);
}

// --- K5: recompute x2 from y2; x4=act(y4)*mask+x2; voxelwise = max_T -------
__global__ void LB_HEAVY k5(const float* __restrict__ y34, const double* __restrict__ st4,
                   const float* __restrict__ g4, const float* __restrict__ b4,
                   const float* __restrict__ y2, const double* __restrict__ st2,
                   const float* __restrict__ g2, const float* __restrict__ b2,
                   const float* __restrict__ vmask, float* __restrict__ vw) {
  __shared__ float ab4[64][2];
  __shared__ float ab2[32][2];
  int t = threadIdx.x;
  if (t < 64) {
    double m = st4[t] / (double)NVT_;
    double var = st4[64 + t] / (double)NVT_ - m * m;
    if (var < 0) var = 0;
    float A = (float)((double)g4[t] / sqrt(var + 1e-5));
    ab4[t][0] = A; ab4[t][1] = b4[t] - (float)m * A;
  } else if (t >= 128 && t < 160) {
    int c = t - 128;
    double m = st2[c] / (double)NVT_;
    double var = st2[32 + c] / (double)NVT_ - m * m;
    if (var < 0) var = 0;
    float A = (float)((double)g2[c] / sqrt(var + 1e-5));
    ab2[c][0] = A; ab2[c][1] = b2[c] - (float)m * A;
  }
  __syncthreads();
  size_t s = (size_t)blockIdx.x * 256 + t;
  int v = (int)(s >> 4), ti = t & 15;
  float msk = vmask[s];
  // x2 = [act2(y2), max_T act2(y2)] * msk  (max taken pre-mask, as reference)
  float xr[64];
  const float4* y2p = (const float4*)(y2 + s * 32);
#pragma unroll
  for (int j = 0; j < 8; j++) {
    float4 f = y2p[j];
    xr[j * 4 + 0] = mishf(f.x * ab2[j * 4 + 0][0] + ab2[j * 4 + 0][1]);
    xr[j * 4 + 1] = mishf(f.y * ab2[j * 4 + 1][0] + ab2[j * 4 + 1][1]);
    xr[j * 4 + 2] = mishf(f.z * ab2[j * 4 + 2][0] + ab2[j * 4 + 2][1]);
    xr[j * 4 + 3] = mishf(f.w * ab2[j * 4 + 3][0] + ab2[j * 4 + 3][1]);
  }
#pragma unroll
  for (int c = 0; c < 32; c++) xr[32 + c] = xr[c];
#pragma unroll
  for (int d = 1; d < 16; d <<= 1) {
#pragma unroll
    for (int c = 0; c < 32; c++)
      xr[32 + c] = fmaxf(xr[32 + c], __shfl_xor(xr[32 + c], d, 64));
  }
#pragma unroll
  for (int c = 0; c < 64; c++) xr[c] *= msk;
  // x4 = act4(y4)*msk + x2
  const float4* yp = (const float4*)(y34 + s * 64);
#pragma unroll
  for (int j = 0; j < 16; j++) {
    float4 f = yp[j];
    xr[j * 4 + 0] += mishf(f.x * ab4[j * 4 + 0][0] + ab4[j * 4 + 0][1]) * msk;
    xr[j * 4 + 1] += mishf(f.y * ab4[j * 4 + 1][0] + ab4[j * 4 + 1][1]) * msk;
    xr[j * 4 + 2] += mishf(f.z * ab4[j * 4 + 2][0] + ab4[j * 4 + 2][1]) * msk;
    xr[j * 4 + 3] += mishf(f.w * ab4[j * 4 + 3][0] + ab4[j * 4 + 3][1]) * msk;
  }
#pragma unroll
  for (int d = 1; d < 16; d <<= 1) {
#pragma unroll
    for (int c = 0; c < 64; c++)
      xr[c] = fmaxf(xr[c], __shfl_xor(xr[c], d, 64));
  }
  *(float4*)(vw + (size_t)v * 64 + ti * 4) =
      make_float4(xr[ti * 4], xr[ti * 4 + 1], xr[ti * 4 + 2], xr[ti * 4 + 3]);
}

// ---------------- K6: stats of grouped einsum-1 output (no materialize) -----
__global__ void LB_HEAVY k6(const float* __restrict__ vw, const int* __restrict__ idx,
                   const float* __restrict__ Wb1, double* __restrict__ sb1) {
  __shared__ float wl[1024];   // wl[(q*8+p)*16 + g]
  __shared__ float lst[256];
  int t = threadIdx.x;
  for (int i = t; i < 1024; i += 256) {
    int g = i >> 6, qp = i & 63;
    wl[qp * 16 + g] = Wb1[i];
  }
  lst[t] = 0.f;
  __syncthreads();
  int g = t & 15, nl = t >> 4;
  float ss[8] = {0, 0, 0, 0, 0, 0, 0, 0}, sq[8] = {0, 0, 0, 0, 0, 0, 0, 0};
  for (int it = 0; it < 16; ++it) {
    int n = blockIdx.x * 256 + it * 16 + nl;
    if (n < NB_) {
      int id[8];
#pragma unroll
      for (int p = 0; p < 8; p++) id[p] = idx[n * 8 + p];
      float xg[4][8];
#pragma unroll
      for (int p = 0; p < 8; p++) {
        float4 f = *(const float4*)(vw + (size_t)id[p] * 64 + g * 4);
        xg[0][p] = f.x; xg[1][p] = f.y; xg[2][p] = f.z; xg[3][p] = f.w;
      }
#pragma unroll
      for (int q = 0; q < 8; q++) {
        float wq[8];
#pragma unroll
        for (int p = 0; p < 8; p++) wq[p] = wl[(q * 8 + p) * 16 + g];
#pragma unroll
        for (int c = 0; c < 4; c++) {
          float a = 0.f;
#pragma unroll
          for (int p = 0; p < 8; p++) a += xg[c][p] * wq[p];
          ss[q] += a; sq[q] += a * a;
        }
      }
    }
  }
#pragma unroll
  for (int d = 16; d < 64; d <<= 1) {
#pragma unroll
    for (int q = 0; q < 8; q++) {
      ss[q] += __shfl_xor(ss[q], d, 64);
      sq[q] += __shfl_xor(sq[q], d, 64);
    }
  }
  if ((t & 48) == 0) {
#pragma unroll
    for (int q = 0; q < 8; q++) {
      atomicAdd(&lst[g * 8 + q], ss[q]);
      atomicAdd(&lst[128 + g * 8 + q], sq[q]);
    }
  }
  __syncthreads();
  atomicAdd(&sb1[t], (double)lst[t]);
}

// ------- K7: recompute einsum1, act, bevmask, einsum2 -> pre17; stats -------
__global__ void LB_HEAVY k7(const float* __restrict__ vw, const int* __restrict__ idx,
                   const float* __restrict__ Wb1, const double* __restrict__ sb1,
                   const float* __restrict__ gb1, const float* __restrict__ bb1,
                   const float* __restrict__ bmask, const float* __restrict__ Wb2,
                   float* __restrict__ pre17, double* __restrict__ sb2) {
  __shared__ float wl[1024];
  __shared__ float w2l[256];   // w2l[(q2*8+q)*16 + g]
  __shared__ float ab[128][2];
  __shared__ float lst[64];
  int t = threadIdx.x;
  for (int i = t; i < 1024; i += 256) {
    int g = i >> 6, qp = i & 63;
    wl[qp * 16 + g] = Wb1[i];
  }
  {
    int g = t >> 4, qq = t & 15;
    w2l[qq * 16 + g] = Wb2[t];
  }
  if (t < 128) {
    double m = sb1[t] / 480000.0;
    double var = sb1[128 + t] / 480000.0 - m * m;
    if (var < 0) var = 0;
    float A = (float)((double)gb1[t] / sqrt(var + 1e-5));
    ab[t][0] = A; ab[t][1] = bb1[t] - (float)m * A;
  }
  if (t < 64) lst[t] = 0.f;
  __syncthreads();
  int g = t & 15, nl = t >> 4;
  float s2[2] = {0, 0}, q2s[2] = {0, 0};
  for (int it = 0; it < 16; ++it) {
    int n = blockIdx.x * 256 + it * 16 + nl;
    if (n < NB_) {
      int id[8];
      float bmv[8];
#pragma unroll
      for (int p = 0; p < 8; p++) { id[p] = idx[n * 8 + p]; bmv[p] = bmask[n * 8 + p]; }
      float xg[4][8];
#pragma unroll
      for (int p = 0; p < 8; p++) {
        float4 f = *(const float4*)(vw + (size_t)id[p] * 64 + g * 4);
        xg[0][p] = f.x; xg[1][p] = f.y; xg[2][p] = f.z; xg[3][p] = f.w;
      }
      float th[4][8];
#pragma unroll
      for (int q = 0; q < 8; q++) {
        float wq[8];
#pragma unroll
        for (int p = 0; p < 8; p++) wq[p] = wl[(q * 8 + p) * 16 + g];
        float A = ab[g * 8 + q][0], B = ab[g * 8 + q][1];
#pragma unroll
        for (int c = 0; c < 4; c++) {
          float a = 0.f;
#pragma unroll
          for (int p = 0; p < 8; p++) a += xg[c][p] * wq[p];
          th[c][q] = mishf(a * A + B) * bmv[q];
        }
      }
#pragma unroll
      for (int c = 0; c < 4; c++) {
        float v0 = 0.f, v1 = 0.f;
#pragma unroll
        for (int q = 0; q < 8; q++) {
          v0 += th[c][q] * w2l[q * 16 + g];
          v1 += th[c][q] * w2l[(8 + q) * 16 + g];
        }
        *(float2*)(pre17 + (size_t)n * 128 + c * 32 + g * 2) = make_float2(v0, v1);
        s2[0] += v0; q2s[0] += v0 * v0;
        s2[1] += v1; q2s[1] += v1 * v1;
      }
    }
  }
#pragma unroll
  for (int d = 16; d < 64; d <<= 1) {
#pragma unroll
    for (int j = 0; j < 2; j++) {
      s2[j] += __shfl_xor(s2[j], d, 64);
      q2s[j] += __shfl_xor(q2s[j], d, 64);
    }
  }
  if ((t & 48) == 0) {
#pragma unroll
    for (int j = 0; j < 2; j++) {
      atomicAdd(&lst[g * 2 + j], s2[j]);
      atomicAdd(&lst[32 + g * 2 + j], q2s[j]);
    }
  }
  __syncthreads();
  if (t < 64) atomicAdd(&sb2[t], (double)lst[t]);
}

// -------- K8/K9: 128x128 GEMM with fused input act (tiled in LDS) ----------
// MODE 0: in = pre17 (x17 order), act via ab[32] (bfe2 BN), write x17, out y18
// MODE 1: in = y18, act via ab[128] (bfe3 BN), out y19 (in-place safe)
template <int MODE>
__global__ void LB_HEAVY kgemm(const float* xin, const double* __restrict__ stin,
                      const float* __restrict__ gam, const float* __restrict__ bet,
                      const float* __restrict__ Wt, float* xact_out,
                      float* yout, double* __restrict__ stout) {
  __shared__ float xs[32 * 129];
  __shared__ float wsh[128 * 33];
  __shared__ float ab[128][2];
  __shared__ float lst[256];
  int t = threadIdx.x;
  const int nch = (MODE == 0) ? 32 : 128;
  const double den = (MODE == 0) ? 480000.0 : 120000.0;
  if (t < nch) {
    double m = stin[t] / den;
    double var = stin[nch + t] / den - m * m;
    if (var < 0) var = 0;
    float A = (float)((double)gam[t] / sqrt(var + 1e-5));
    ab[t][0] = A; ab[t][1] = bet[t] - (float)m * A;
  }
  lst[t] = 0.f;
  __syncthreads();
  int s0 = blockIdx.x * 128;
  int oc = t & 7, sc = t >> 3;
  int cl = t & 31, sl8 = t >> 5;
  float acc[64];
#pragma unroll
  for (int i = 0; i < 64; i++) acc[i] = 0.f;
  for (int cb = 0; cb < 128; cb += 32) {
#pragma unroll
    for (int r = 0; r < 16; r++) {
      int slocal = r * 8 + sl8;
      int sg = s0 + slocal;
      float v = 0.f;
      if (sg < NB_) {
        float h = xin[(size_t)sg * 128 + cb + cl];
        if (MODE == 0) {
          v = mishf(h * ab[cl][0] + ab[cl][1]);
          xact_out[(size_t)sg * 128 + cb + cl] = v;
        } else {
          v = mishf(h * ab[cb + cl][0] + ab[cb + cl][1]);
        }
      }
      xs[cl * 129 + slocal] = v;
    }
#pragma unroll
    for (int r = 0; r < 16; r++) {
      int o = r * 8 + sl8;
      wsh[o * 33 + cl] = Wt[o * 128 + cb + cl];
    }
    __syncthreads();
#pragma unroll 4
    for (int c = 0; c < 32; c++) {
      float xv[4];
#pragma unroll
      for (int i = 0; i < 4; i++) xv[i] = xs[c * 129 + sc * 4 + i];
#pragma unroll
      for (int k = 0; k < 16; k++) {
        float wv = wsh[(k * 8 + oc) * 33 + c];
#pragma unroll
        for (int i = 0; i < 4; i++) acc[k * 4 + i] += wv * xv[i];
      }
    }
    __syncthreads();
  }
  float ssum[16], ssq[16];
#pragma unroll
  for (int k = 0; k < 16; k++) { ssum[k] = 0.f; ssq[k] = 0.f; }
#pragma unroll
  for (int i = 0; i < 4; i++) {
    int sg = s0 + sc * 4 + i;
    if (sg < NB_) {
#pragma unroll
      for (int k = 0; k < 16; k++) {
        float v = acc[k * 4 + i];
        yout[(size_t)sg * 128 + k * 8 + oc] = v;
        ssum[k] += v; ssq[k] += v * v;
      }
    }
  }
#pragma unroll
  for (int d = 8; d < 64; d <<= 1) {
#pragma unroll
    for (int k = 0; k < 16; k++) {
      ssum[k] += __shfl_xor(ssum[k], d, 64);
      ssq[k] += __shfl_xor(ssq[k], d, 64);
    }
  }
  if ((t & 63) < 8) {
#pragma unroll
    for (int k = 0; k < 16; k++) {
      atomicAdd(&lst[k * 8 + oc], ssum[k]);
      atomicAdd(&lst[128 + k * 8 + oc], ssq[k]);
    }
  }
  __syncthreads();
  atomicAdd(&stout[t], (double)lst[t]);
}

// ------- K10: x19 = act(y19)+x17, transposed coalesced write of output ------
__global__ void LB_LIGHT k10(const float* __restrict__ y19, const float* __restrict__ x17,
                    const double* __restrict__ s19, const float* __restrict__ g3,
                    const float* __restrict__ b3, const int* __restrict__ inv,
                    float* __restrict__ out) {
  __shared__ float buf[256 * 32];
  __shared__ float ab[32][2];
  int t = threadIdx.x;
  int w = blockIdx.x, hh = blockIdx.y, ch = blockIdx.z;
  if (t < 32) {
    int c = ch * 32 + t;
    double m = s19[c] / 120000.0;
    double var = s19[128 + c] / 120000.0 - m * m;
    if (var < 0) var = 0;
    float A = (float)((double)g3[c] / sqrt(var + 1e-5));
    ab[t][0] = A; ab[t][1] = b3[c] - (float)m * A;
  }
  __syncthreads();
  int lane = t & 31, rg = t >> 5;
#pragma unroll 4
  for (int r = 0; r < 32; r++) {
    int h_l = r * 8 + rg;
    int h = hh * 256 + h_l;
    int n = inv[h * W_ + w];
    float v = 0.f;
    if (n >= 0) {
      float y = y19[(size_t)n * 128 + ch * 32 + lane];
      v = mishf(y * ab[lane][0] + ab[lane][1]) +
          x17[(size_t)n * 128 + ch * 32 + lane];
    }
    buf[h_l * 32 + (lane ^ (h_l & 31))] = v;
  }
  __syncthreads();
#pragma unroll 4
  for (int c_l = 0; c_l < 32; c_l++) {
    out[(size_t)(ch * 32 + c_l) * (W_ * H_) + (size_t)w * H_ + hh * 256 + t] =
        buf[t * 32 + (c_l ^ (t & 31))];
  }
}

extern "C" void kernel_launch(void* const* d_in, const int* in_sizes, int n_in,
                              void* d_out, int out_size, void* d_ws, size_t ws_size,
                              hipStream_t stream) {
  const float* voxels = (const float*)d_in[0];
  const float* vmask = (const float*)d_in[1];
  const float* bmask = (const float*)d_in[2];
  const float* W1 = (const float*)d_in[3];
  const float* g1 = (const float*)d_in[4];
  const float* b1 = (const float*)d_in[5];
  const float* W2 = (const float*)d_in[6];
  const float* g2 = (const float*)d_in[7];
  const float* b2 = (const float*)d_in[8];
  const float* W3 = (const float*)d_in[9];
  const float* g3 = (const float*)d_in[10];
  const float* b3 = (const float*)d_in[11];
  const float* W4 = (const float*)d_in[12];
  const float* g4 = (const float*)d_in[13];
  const float* b4 = (const float*)d_in[14];
  const float* Wb1 = (const float*)d_in[15];
  const float* gb1 = (const float*)d_in[16];
  const float* bb1 = (const float*)d_in[17];
  const float* Wb2 = (const float*)d_in[18];
  const float* gb2 = (const float*)d_in[19];
  const float* bb2 = (const float*)d_in[20];
  const float* Wb3 = (const float*)d_in[21];
  const float* gb3 = (const float*)d_in[22];
  const float* bb3 = (const float*)d_in[23];
  const int* bevsidx = (const int*)d_in[24];
  const int* bevcoors = (const int*)d_in[25];

  float* ws = (float*)d_ws;
  float* y1 = ws + OF_Y1;
  float* y2 = ws + OF_Y2;
  float* y34 = ws + OF_Y34;
  float* vw = ws + OF_VW;
  float* pre17 = ws + OF_PRE17;
  float* x17 = ws + OF_X17;
  float* y1819 = ws + OF_Y1819;
  int* inv = (int*)(ws + OF_INV);
  double* stats = (double*)((char*)d_ws + STATS_BYTE);

  hipMemsetAsync(stats, 0, D_TOTAL * sizeof(double), stream);
  hipMemsetAsync(inv, 0xFF, (size_t)(H_ * W_) * sizeof(int), stream);

  k_inv<<<469, 256, 0, stream>>>(bevcoors, inv);
  k1<<<3125, 256, 0, stream>>>(voxels, W1, y1, stats + D_ST1);
  k2<<<3125, 256, 0, stream>>>(y1, stats + D_ST1, g1, b1, W2, y2, stats + D_ST2);
  k3<<<3125, 256, 0, stream>>>(y2, stats + D_ST2, g2, b2, vmask, W3, y34,
                               stats + D_ST3);
  k4<<<3125, 256, 0, stream>>>(y34, stats + D_ST3, g3, b3, W4, stats + D_ST4);
  k5<<<3125, 256, 0, stream>>>(y34, stats + D_ST4, g4, b4, y2, stats + D_ST2,
                               g2, b2, vmask, vw);
  k6<<<469, 256, 0, stream>>>(vw, bevsidx, Wb1, stats + D_SB1);
  k7<<<469, 256, 0, stream>>>(vw, bevsidx, Wb1, stats + D_SB1, gb1, bb1, bmask,
                              Wb2, pre17, stats + D_SB2);
  kgemm<0><<<938, 256, 0, stream>>>(pre17, stats + D_SB2, gb2, bb2, Wb3, x17,
                                    y1819, stats + D_S18);
  kgemm<1><<<938, 256, 0, stream>>>(y1819, stats + D_S18, gb3, bb3, Wb3, nullptr,
                                    y1819, stats + D_S19);
  dim3 g10(512, 2, 4);
  k10<<<g10, 256, 0, stream>>>(y1819, x17, stats + D_S19, gb3, bb3, inv,
                               (float*)d_out);
}

// Round 8
// 1707.476 us; speedup vs baseline: 2.8111x; 1.8606x over previous
//
#include <hip/hip_runtime.h>
#include <math.h>

#define NV_   50000
#define T16_  16
#define NVT_  800000
#define NB_   120000
#define G_    16
#define P_    8
#define H_    512
#define W_    512

// ---- workspace layout (float element offsets) ----
// y34 region (51.2M floats) is reused after K5 for pre17/x17/y1819.
#define OF_Y34    0ul            // 51.2M  y3 then y4 in-place [K3..K5]
#define OF_Y2     51200000ul     // 25.6M  [K2..K5]
#define OF_Y1     76800000ul     // 6.4M   [K1..K2]
#define OF_VW     83200000ul     // 3.2M   [K5..K7]
#define OF_INV    86400000ul     // 262144 ints [Kinv..K10]
#define OF_PRE17  0ul            // 15.36M (reuse y34) [K7..K8]
#define OF_X17    16000000ul     // 15.36M (reuse y34) [K8..K10]
#define OF_Y1819  32000000ul     // 15.36M (reuse y34) y18 then y19 in-place
#define STATS_BYTE 346648576ul   // (86400000+262144)*4, 8B aligned

// stats (double) offsets: layout per layer = sum[C] then sumsq[C]
#define D_ST1 0
#define D_ST2 16
#define D_ST3 80
#define D_ST4 208
#define D_SB1 336
#define D_SB2 592
#define D_S18 656
#define D_S19 912
#define D_TOTAL 1168

// VGPR-cap control: 2 waves/EU -> ~256 VGPRs (no spill for xr[64]-style kernels)
#define LB_HEAVY __launch_bounds__(256, 2)
#define LB_LIGHT __launch_bounds__(256, 4)

__device__ __forceinline__ float mishf(float x) {
  // x * tanh(softplus(x)) == x - 2x/((1+e^x)^2 + 1); robust at +-inf
  float e = __expf(x);
  float u = 1.0f + e;
  return x - 2.0f * x / (u * u + 1.0f);
}

template <int N>
__device__ __forceinline__ void wave_red_sum(float* v) {
#pragma unroll
  for (int d = 1; d < 64; d <<= 1) {
#pragma unroll
    for (int i = 0; i < N; i++) v[i] += __shfl_xor(v[i], d, 64);
  }
}

// ---------------- inverse scatter map ----------------
__global__ void LB_LIGHT k_inv(const int* __restrict__ coors, int* __restrict__ inv) {
  int n = blockIdx.x * 256 + threadIdx.x;
  if (n < NB_) {
    int h = coors[2 * n], w = coors[2 * n + 1];
    inv[h * W_ + w] = n;
  }
}

// ---------------- K1: y1 = voxels @ W1^T, stats(y1) ----------------
__global__ void LB_LIGHT k1(const float* __restrict__ vox, const float* __restrict__ W1,
                   float* __restrict__ y1, double* __restrict__ st) {
  __shared__ float wl[64];
  __shared__ float lst[16];
  int t = threadIdx.x;
  if (t < 64) wl[t] = W1[t];
  if (t < 16) lst[t] = 0.f;
  __syncthreads();
  size_t s = (size_t)blockIdx.x * 256 + t;
  const float4* vp = (const float4*)(vox + s * 8);
  float4 a0 = vp[0], a1 = vp[1];
  float x[8] = {a0.x, a0.y, a0.z, a0.w, a1.x, a1.y, a1.z, a1.w};
  float y[8];
#pragma unroll
  for (int o = 0; o < 8; o++) {
    float a = 0.f;
#pragma unroll
    for (int c = 0; c < 8; c++) a += x[c] * wl[o * 8 + c];
    y[o] = a;
  }
  float4* yp = (float4*)(y1 + s * 8);
  yp[0] = make_float4(y[0], y[1], y[2], y[3]);
  yp[1] = make_float4(y[4], y[5], y[6], y[7]);
  float v[16];
#pragma unroll
  for (int i = 0; i < 8; i++) { v[i] = y[i]; v[8 + i] = y[i] * y[i]; }
  wave_red_sum<16>(v);
  if ((t & 63) == 0) {
#pragma unroll
    for (int i = 0; i < 16; i++) atomicAdd(&lst[i], v[i]);
  }
  __syncthreads();
  if (t < 16) atomicAdd(&st[t], (double)lst[t]);
}

// ---------------- K2: p1=act(y1); max_T; y2 = [p1,a] @ W2^T; stats(y2) ------
__global__ void LB_HEAVY k2(const float* __restrict__ y1, const double* __restrict__ st1,
                   const float* __restrict__ g1, const float* __restrict__ b1,
                   const float* __restrict__ W2, float* __restrict__ y2,
                   double* __restrict__ st2) {
  __shared__ float wl[512];
  __shared__ float ab[8][2];
  __shared__ float lst[64];
  int t = threadIdx.x;
  wl[t] = W2[t];                 // 256 threads: two elements each
  wl[256 + t] = W2[256 + t];
  if (t < 8) {
    double m = st1[t] / (double)NVT_;
    double var = st1[8 + t] / (double)NVT_ - m * m;
    if (var < 0) var = 0;
    float A = (float)((double)g1[t] / sqrt(var + 1e-5));
    ab[t][0] = A; ab[t][1] = b1[t] - (float)m * A;
  }
  if (t < 64) lst[t] = 0.f;
  __syncthreads();
  size_t s = (size_t)blockIdx.x * 256 + t;  // (voxel, ti) = (s/16, s%16)
  const float4* yp = (const float4*)(y1 + s * 8);
  float4 f0 = yp[0], f1 = yp[1];
  float in[8] = {f0.x, f0.y, f0.z, f0.w, f1.x, f1.y, f1.z, f1.w};
  float xr[16];
#pragma unroll
  for (int c = 0; c < 8; c++) xr[c] = mishf(in[c] * ab[c][0] + ab[c][1]);
#pragma unroll
  for (int c = 0; c < 8; c++) xr[8 + c] = xr[c];
#pragma unroll
  for (int d = 1; d < 16; d <<= 1) {
#pragma unroll
    for (int c = 0; c < 8; c++)
      xr[8 + c] = fmaxf(xr[8 + c], __shfl_xor(xr[8 + c], d, 64));
  }
  float yo[32];
#pragma unroll
  for (int o = 0; o < 32; o++) {
    float a = 0.f;
    const float4* wp = (const float4*)(wl + o * 16);
#pragma unroll
    for (int c4 = 0; c4 < 4; c4++) {
      float4 w4 = wp[c4];
      a += xr[c4 * 4 + 0] * w4.x + xr[c4 * 4 + 1] * w4.y +
           xr[c4 * 4 + 2] * w4.z + xr[c4 * 4 + 3] * w4.w;
    }
    yo[o] = a;
  }
  float4* op = (float4*)(y2 + s * 32);
#pragma unroll
  for (int j = 0; j < 8; j++)
    op[j] = make_float4(yo[j * 4], yo[j * 4 + 1], yo[j * 4 + 2], yo[j * 4 + 3]);
#pragma unroll
  for (int ch = 0; ch < 4; ch++) {
    float v[16];
#pragma unroll
    for (int i = 0; i < 8; i++) {
      v[i] = yo[ch * 8 + i]; v[8 + i] = v[i] * v[i];
    }
    wave_red_sum<16>(v);
    if ((t & 63) == 0) {
#pragma unroll
      for (int i = 0; i < 8; i++) {
        atomicAdd(&lst[ch * 8 + i], v[i]);
        atomicAdd(&lst[32 + ch * 8 + i], v[8 + i]);
      }
    }
  }
  __syncthreads();
  if (t < 64) atomicAdd(&st2[t], (double)lst[t]);
}

// ------- K3: x2 = [act(y2),max]*mask (in regs); y3 = x2 @ W3^T; stats(y3) ---
// Weights read DIRECTLY from global: address is wave-uniform -> compiler
// scalarizes to s_load (SMEM pipe, SGPR operand), zero LDS traffic.
__global__ void LB_HEAVY k3(const float* __restrict__ y2, const double* __restrict__ st2,
                   const float* __restrict__ g2, const float* __restrict__ b2,
                   const float* __restrict__ vmask, const float* __restrict__ W3,
                   float* __restrict__ y3, double* __restrict__ st3) {
  __shared__ float ab[32][2];
  __shared__ float lst[128];
  int t = threadIdx.x;
  if (t < 32) {
    double m = st2[t] / (double)NVT_;
    double var = st2[32 + t] / (double)NVT_ - m * m;
    if (var < 0) var = 0;
    float A = (float)((double)g2[t] / sqrt(var + 1e-5));
    ab[t][0] = A; ab[t][1] = b2[t] - (float)m * A;
  }
  if (t < 128) lst[t] = 0.f;
  __syncthreads();
  size_t s = (size_t)blockIdx.x * 256 + t;
  float xr[64];
  const float4* yp = (const float4*)(y2 + s * 32);
#pragma unroll
  for (int j = 0; j < 8; j++) {
    float4 f = yp[j];
    xr[j * 4 + 0] = mishf(f.x * ab[j * 4 + 0][0] + ab[j * 4 + 0][1]);
    xr[j * 4 + 1] = mishf(f.y * ab[j * 4 + 1][0] + ab[j * 4 + 1][1]);
    xr[j * 4 + 2] = mishf(f.z * ab[j * 4 + 2][0] + ab[j * 4 + 2][1]);
    xr[j * 4 + 3] = mishf(f.w * ab[j * 4 + 3][0] + ab[j * 4 + 3][1]);
  }
#pragma unroll
  for (int c = 0; c < 32; c++) xr[32 + c] = xr[c];
#pragma unroll
  for (int d = 1; d < 16; d <<= 1) {
#pragma unroll
    for (int c = 0; c < 32; c++)
      xr[32 + c] = fmaxf(xr[32 + c], __shfl_xor(xr[32 + c], d, 64));
  }
  float m = vmask[s];
#pragma unroll
  for (int c = 0; c < 64; c++) xr[c] *= m;
#pragma unroll
  for (int oc = 0; oc < 4; oc++) {
    float yo[16];
#pragma unroll
    for (int o = 0; o < 16; o++) {
      float a = 0.f;
      const float4* wp = (const float4*)(W3 + (oc * 16 + o) * 64);  // uniform -> s_load
#pragma unroll
      for (int c4 = 0; c4 < 16; c4++) {
        float4 w4 = wp[c4];
        a += xr[c4 * 4 + 0] * w4.x + xr[c4 * 4 + 1] * w4.y +
             xr[c4 * 4 + 2] * w4.z + xr[c4 * 4 + 3] * w4.w;
      }
      yo[o] = a;
    }
    float4* op = (float4*)(y3 + s * 64 + oc * 16);
#pragma unroll
    for (int j = 0; j < 4; j++)
      op[j] = make_float4(yo[j * 4], yo[j * 4 + 1], yo[j * 4 + 2], yo[j * 4 + 3]);
    float v[32];
#pragma unroll
    for (int i = 0; i < 16; i++) { v[i] = yo[i]; v[16 + i] = yo[i] * yo[i]; }
    wave_red_sum<32>(v);
    if ((t & 63) == 0) {
#pragma unroll
      for (int i = 0; i < 16; i++) {
        atomicAdd(&lst[oc * 16 + i], v[i]);
        atomicAdd(&lst[64 + oc * 16 + i], v[16 + i]);
      }
    }
  }
  __syncthreads();
  if (t < 128) atomicAdd(&st3[t], (double)lst[t]);
}

// ---------------- K4: x3=act(y3); y4 = x3 @ W4^T (in-place); stats(y4) ------
__global__ void LB_HEAVY k4(float* y34, const double* __restrict__ st3,
                   const float* __restrict__ g3, const float* __restrict__ b3,
                   const float* __restrict__ W4, double* __restrict__ st4) {
  __shared__ float ab[64][2];
  __shared__ float lst[128];
  int t = threadIdx.x;
  if (t < 64) {
    double m = st3[t] / (double)NVT_;
    double var = st3[64 + t] / (double)NVT_ - m * m;
    if (var < 0) var = 0;
    float A = (float)((double)g3[t] / sqrt(var + 1e-5));
    ab[t][0] = A; ab[t][1] = b3[t] - (float)m * A;
  }
  if (t < 128) lst[t] = 0.f;
  __syncthreads();
  size_t s = (size_t)blockIdx.x * 256 + t;
  float xr[64];
  const float4* yp = (const float4*)(y34 + s * 64);
#pragma unroll
  for (int j = 0; j < 16; j++) {
    float4 f = yp[j];
    xr[j * 4 + 0] = mishf(f.x * ab[j * 4 + 0][0] + ab[j * 4 + 0][1]);
    xr[j * 4 + 1] = mishf(f.y * ab[j * 4 + 1][0] + ab[j * 4 + 1][1]);
    xr[j * 4 + 2] = mishf(f.z * ab[j * 4 + 2][0] + ab[j * 4 + 2][1]);
    xr[j * 4 + 3] = mishf(f.w * ab[j * 4 + 3][0] + ab[j * 4 + 3][1]);
  }
#pragma unroll
  for (int oc = 0; oc < 4; oc++) {
    float yo[16];
#pragma unroll
    for (int o = 0; o < 16; o++) {
      float a = 0.f;
      const float4* wp = (const float4*)(W4 + (oc * 16 + o) * 64);  // uniform -> s_load
#pragma unroll
      for (int c4 = 0; c4 < 16; c4++) {
        float4 w4 = wp[c4];
        a += xr[c4 * 4 + 0] * w4.x + xr[c4 * 4 + 1] * w4.y +
             xr[c4 * 4 + 2] * w4.z + xr[c4 * 4 + 3] * w4.w;
      }
      yo[o] = a;
    }
    float4* op = (float4*)(y34 + s * 64 + oc * 16);
#pragma unroll
    for (int j = 0; j < 4; j++)
      op[j] = make_float4(yo[j * 4], yo[j * 4 + 1], yo[j * 4 + 2], yo[j * 4 + 3]);
    float v[32];
#pragma unroll
    for (int i = 0; i < 16; i++) { v[i] = yo[i]; v[16 + i] = yo[i] * yo[i]; }
    wave_red_sum<32>(v);
    if ((t & 63) == 0) {
#pragma unroll
      for (int i = 0; i < 16; i++) {
        atomicAdd(&lst[oc * 16 + i], v[i]);
        atomicAdd(&lst[64 + oc * 16 + i], v[16 + i]);
      }
    }
  }
  __syncthreads();
  if (t < 128) atomicAdd(&st4[t], (double)lst[t]);
}

// --- K5: recompute x2 from y2; x4=act(y4)*mask+x2; voxelwise = max_T -------
__global__ void LB_HEAVY k5(const float* __restrict__ y34, const double* __restrict__ st4,
                   const float* __restrict__ g4, const float* __restrict__ b4,
                   const float* __restrict__ y2, const double* __restrict__ st2,
                   const float* __restrict__ g2, const float* __restrict__ b2,
                   const float* __restrict__ vmask, float* __restrict__ vw) {
  __shared__ float ab4[64][2];
  __shared__ float ab2[32][2];
  int t = threadIdx.x;
  if (t < 64) {
    double m = st4[t] / (double)NVT_;
    double var = st4[64 + t] / (double)NVT_ - m * m;
    if (var < 0) var = 0;
    float A = (float)((double)g4[t] / sqrt(var + 1e-5));
    ab4[t][0] = A; ab4[t][1] = b4[t] - (float)m * A;
  } else if (t >= 128 && t < 160) {
    int c = t - 128;
    double m = st2[c] / (double)NVT_;
    double var = st2[32 + c] / (double)NVT_ - m * m;
    if (var < 0) var = 0;
    float A = (float)((double)g2[c] / sqrt(var + 1e-5));
    ab2[c][0] = A; ab2[c][1] = b2[c] - (float)m * A;
  }
  __syncthreads();
  size_t s = (size_t)blockIdx.x * 256 + t;
  int v = (int)(s >> 4), ti = t & 15;
  float msk = vmask[s];
  // x2 = [act2(y2), max_T act2(y2)] * msk  (max taken pre-mask, as reference)
  float xr[64];
  const float4* y2p = (const float4*)(y2 + s * 32);
#pragma unroll
  for (int j = 0; j < 8; j++) {
    float4 f = y2p[j];
    xr[j * 4 + 0] = mishf(f.x * ab2[j * 4 + 0][0] + ab2[j * 4 + 0][1]);
    xr[j * 4 + 1] = mishf(f.y * ab2[j * 4 + 1][0] + ab2[j * 4 + 1][1]);
    xr[j * 4 + 2] = mishf(f.z * ab2[j * 4 + 2][0] + ab2[j * 4 + 2][1]);
    xr[j * 4 + 3] = mishf(f.w * ab2[j * 4 + 3][0] + ab2[j * 4 + 3][1]);
  }
#pragma unroll
  for (int c = 0; c < 32; c++) xr[32 + c] = xr[c];
#pragma unroll
  for (int d = 1; d < 16; d <<= 1) {
#pragma unroll
    for (int c = 0; c < 32; c++)
      xr[32 + c] = fmaxf(xr[32 + c], __shfl_xor(xr[32 + c], d, 64));
  }
#pragma unroll
  for (int c = 0; c < 64; c++) xr[c] *= msk;
  // x4 = act4(y4)*msk + x2
  const float4* yp = (const float4*)(y34 + s * 64);
#pragma unroll
  for (int j = 0; j < 16; j++) {
    float4 f = yp[j];
    xr[j * 4 + 0] += mishf(f.x * ab4[j * 4 + 0][0] + ab4[j * 4 + 0][1]) * msk;
    xr[j * 4 + 1] += mishf(f.y * ab4[j * 4 + 1][0] + ab4[j * 4 + 1][1]) * msk;
    xr[j * 4 + 2] += mishf(f.z * ab4[j * 4 + 2][0] + ab4[j * 4 + 2][1]) * msk;
    xr[j * 4 + 3] += mishf(f.w * ab4[j * 4 + 3][0] + ab4[j * 4 + 3][1]) * msk;
  }
#pragma unroll
  for (int d = 1; d < 16; d <<= 1) {
#pragma unroll
    for (int c = 0; c < 64; c++)
      xr[c] = fmaxf(xr[c], __shfl_xor(xr[c], d, 64));
  }
  *(float4*)(vw + (size_t)v * 64 + ti * 4) =
      make_float4(xr[ti * 4], xr[ti * 4 + 1], xr[ti * 4 + 2], xr[ti * 4 + 3]);
}

// ---------------- K6: stats of grouped einsum-1 output (no materialize) -----
__global__ void LB_HEAVY k6(const float* __restrict__ vw, const int* __restrict__ idx,
                   const float* __restrict__ Wb1, double* __restrict__ sb1) {
  __shared__ float wl[1024];   // wl[(q*8+p)*16 + g]
  __shared__ float lst[256];
  int t = threadIdx.x;
  for (int i = t; i < 1024; i += 256) {
    int g = i >> 6, qp = i & 63;
    wl[qp * 16 + g] = Wb1[i];
  }
  lst[t] = 0.f;
  __syncthreads();
  int g = t & 15, nl = t >> 4;
  float ss[8] = {0, 0, 0, 0, 0, 0, 0, 0}, sq[8] = {0, 0, 0, 0, 0, 0, 0, 0};
  for (int it = 0; it < 16; ++it) {
    int n = blockIdx.x * 256 + it * 16 + nl;
    if (n < NB_) {
      int id[8];
#pragma unroll
      for (int p = 0; p < 8; p++) id[p] = idx[n * 8 + p];
      float xg[4][8];
#pragma unroll
      for (int p = 0; p < 8; p++) {
        float4 f = *(const float4*)(vw + (size_t)id[p] * 64 + g * 4);
        xg[0][p] = f.x; xg[1][p] = f.y; xg[2][p] = f.z; xg[3][p] = f.w;
      }
#pragma unroll
      for (int q = 0; q < 8; q++) {
        float wq[8];
#pragma unroll
        for (int p = 0; p < 8; p++) wq[p] = wl[(q * 8 + p) * 16 + g];
#pragma unroll
        for (int c = 0; c < 4; c++) {
          float a = 0.f;
#pragma unroll
          for (int p = 0; p < 8; p++) a += xg[c][p] * wq[p];
          ss[q] += a; sq[q] += a * a;
        }
      }
    }
  }
#pragma unroll
  for (int d = 16; d < 64; d <<= 1) {
#pragma unroll
    for (int q = 0; q < 8; q++) {
      ss[q] += __shfl_xor(ss[q], d, 64);
      sq[q] += __shfl_xor(sq[q], d, 64);
    }
  }
  if ((t & 48) == 0) {
#pragma unroll
    for (int q = 0; q < 8; q++) {
      atomicAdd(&lst[g * 8 + q], ss[q]);
      atomicAdd(&lst[128 + g * 8 + q], sq[q]);
    }
  }
  __syncthreads();
  atomicAdd(&sb1[t], (double)lst[t]);
}

// ------- K7: recompute einsum1, act, bevmask, einsum2 -> pre17; stats -------
__global__ void LB_HEAVY k7(const float* __restrict__ vw, const int* __restrict__ idx,
                   const float* __restrict__ Wb1, const double* __restrict__ sb1,
                   const float* __restrict__ gb1, const float* __restrict__ bb1,
                   const float* __restrict__ bmask, const float* __restrict__ Wb2,
                   float* __restrict__ pre17, double* __restrict__ sb2) {
  __shared__ float wl[1024];
  __shared__ float w2l[256];   // w2l[(q2*8+q)*16 + g]
  __shared__ float ab[128][2];
  __shared__ float lst[64];
  int t = threadIdx.x;
  for (int i = t; i < 1024; i += 256) {
    int g = i >> 6, qp = i & 63;
    wl[qp * 16 + g] = Wb1[i];
  }
  {
    int g = t >> 4, qq = t & 15;
    w2l[qq * 16 + g] = Wb2[t];
  }
  if (t < 128) {
    double m = sb1[t] / 480000.0;
    double var = sb1[128 + t] / 480000.0 - m * m;
    if (var < 0) var = 0;
    float A = (float)((double)gb1[t] / sqrt(var + 1e-5));
    ab[t][0] = A; ab[t][1] = bb1[t] - (float)m * A;
  }
  if (t < 64) lst[t] = 0.f;
  __syncthreads();
  int g = t & 15, nl = t >> 4;
  float s2[2] = {0, 0}, q2s[2] = {0, 0};
  for (int it = 0; it < 16; ++it) {
    int n = blockIdx.x * 256 + it * 16 + nl;
    if (n < NB_) {
      int id[8];
      float bmv[8];
#pragma unroll
      for (int p = 0; p < 8; p++) { id[p] = idx[n * 8 + p]; bmv[p] = bmask[n * 8 + p]; }
      float xg[4][8];
#pragma unroll
      for (int p = 0; p < 8; p++) {
        float4 f = *(const float4*)(vw + (size_t)id[p] * 64 + g * 4);
        xg[0][p] = f.x; xg[1][p] = f.y; xg[2][p] = f.z; xg[3][p] = f.w;
      }
      float th[4][8];
#pragma unroll
      for (int q = 0; q < 8; q++) {
        float wq[8];
#pragma unroll
        for (int p = 0; p < 8; p++) wq[p] = wl[(q * 8 + p) * 16 + g];
        float A = ab[g * 8 + q][0], B = ab[g * 8 + q][1];
#pragma unroll
        for (int c = 0; c < 4; c++) {
          float a = 0.f;
#pragma unroll
          for (int p = 0; p < 8; p++) a += xg[c][p] * wq[p];
          th[c][q] = mishf(a * A + B) * bmv[q];
        }
      }
#pragma unroll
      for (int c = 0; c < 4; c++) {
        float v0 = 0.f, v1 = 0.f;
#pragma unroll
        for (int q = 0; q < 8; q++) {
          v0 += th[c][q] * w2l[q * 16 + g];
          v1 += th[c][q] * w2l[(8 + q) * 16 + g];
        }
        *(float2*)(pre17 + (size_t)n * 128 + c * 32 + g * 2) = make_float2(v0, v1);
        s2[0] += v0; q2s[0] += v0 * v0;
        s2[1] += v1; q2s[1] += v1 * v1;
      }
    }
  }
#pragma unroll
  for (int d = 16; d < 64; d <<= 1) {
#pragma unroll
    for (int j = 0; j < 2; j++) {
      s2[j] += __shfl_xor(s2[j], d, 64);
      q2s[j] += __shfl_xor(q2s[j], d, 64);
    }
  }
  if ((t & 48) == 0) {
#pragma unroll
    for (int j = 0; j < 2; j++) {
      atomicAdd(&lst[g * 2 + j], s2[j]);
      atomicAdd(&lst[32 + g * 2 + j], q2s[j]);
    }
  }
  __syncthreads();
  if (t < 64) atomicAdd(&sb2[t], (double)lst[t]);
}

// -------- K8/K9: 128x128 GEMM with fused input act (tiled in LDS) ----------
// MODE 0: in = pre17 (x17 order), act via ab[32] (bfe2 BN), write x17, out y18
// MODE 1: in = y18, act via ab[128] (bfe3 BN), out y19 (in-place safe)
template <int MODE>
__global__ void LB_HEAVY kgemm(const float* xin, const double* __restrict__ stin,
                      const float* __restrict__ gam, const float* __restrict__ bet,
                      const float* __restrict__ Wt, float* xact_out,
                      float* yout, double* __restrict__ stout) {
  __shared__ float xs[32 * 129];
  __shared__ float wsh[128 * 33];
  __shared__ float ab[128][2];
  __shared__ float lst[256];
  int t = threadIdx.x;
  const int nch = (MODE == 0) ? 32 : 128;
  const double den = (MODE == 0) ? 480000.0 : 120000.0;
  if (t < nch) {
    double m = stin[t] / den;
    double var = stin[nch + t] / den - m * m;
    if (var < 0) var = 0;
    float A = (float)((double)gam[t] / sqrt(var + 1e-5));
    ab[t][0] = A; ab[t][1] = bet[t] - (float)m * A;
  }
  lst[t] = 0.f;
  __syncthreads();
  int s0 = blockIdx.x * 128;
  int oc = t & 7, sc = t >> 3;
  int cl = t & 31, sl8 = t >> 5;
  float acc[64];
#pragma unroll
  for (int i = 0; i < 64; i++) acc[i] = 0.f;
  for (int cb = 0; cb < 128; cb += 32) {
#pragma unroll
    for (int r = 0; r < 16; r++) {
      int slocal = r * 8 + sl8;
      int sg = s0 + slocal;
      float v = 0.f;
      if (sg < NB_) {
        float h = xin[(size_t)sg * 128 + cb + cl];
        if (MODE == 0) {
          v = mishf(h * ab[cl][0] + ab[cl][1]);
          xact_out[(size_t)sg * 128 + cb + cl] = v;
        } else {
          v = mishf(h * ab[cb + cl][0] + ab[cb + cl][1]);
        }
      }
      xs[cl * 129 + slocal] = v;
    }
#pragma unroll
    for (int r = 0; r < 16; r++) {
      int o = r * 8 + sl8;
      wsh[o * 33 + cl] = Wt[o * 128 + cb + cl];
    }
    __syncthreads();
#pragma unroll 4
    for (int c = 0; c < 32; c++) {
      float xv[4];
#pragma unroll
      for (int i = 0; i < 4; i++) xv[i] = xs[c * 129 + sc * 4 + i];
#pragma unroll
      for (int k = 0; k < 16; k++) {
        float wv = wsh[(k * 8 + oc) * 33 + c];
#pragma unroll
        for (int i = 0; i < 4; i++) acc[k * 4 + i] += wv * xv[i];
      }
    }
    __syncthreads();
  }
  float ssum[16], ssq[16];
#pragma unroll
  for (int k = 0; k < 16; k++) { ssum[k] = 0.f; ssq[k] = 0.f; }
#pragma unroll
  for (int i = 0; i < 4; i++) {
    int sg = s0 + sc * 4 + i;
    if (sg < NB_) {
#pragma unroll
      for (int k = 0; k < 16; k++) {
        float v = acc[k * 4 + i];
        yout[(size_t)sg * 128 + k * 8 + oc] = v;
        ssum[k] += v; ssq[k] += v * v;
      }
    }
  }
#pragma unroll
  for (int d = 8; d < 64; d <<= 1) {
#pragma unroll
    for (int k = 0; k < 16; k++) {
      ssum[k] += __shfl_xor(ssum[k], d, 64);
      ssq[k] += __shfl_xor(ssq[k], d, 64);
    }
  }
  if ((t & 63) < 8) {
#pragma unroll
    for (int k = 0; k < 16; k++) {
      atomicAdd(&lst[k * 8 + oc], ssum[k]);
      atomicAdd(&lst[128 + k * 8 + oc], ssq[k]);
    }
  }
  __syncthreads();
  atomicAdd(&stout[t], (double)lst[t]);
}

// ------- K10: x19 = act(y19)+x17, transposed coalesced write of output ------
__global__ void LB_LIGHT k10(const float* __restrict__ y19, const float* __restrict__ x17,
                    const double* __restrict__ s19, const float* __restrict__ g3,
                    const float* __restrict__ b3, const int* __restrict__ inv,
                    float* __restrict__ out) {
  __shared__ float buf[256 * 32];
  __shared__ float ab[32][2];
  int t = threadIdx.x;
  int w = blockIdx.x, hh = blockIdx.y, ch = blockIdx.z;
  if (t < 32) {
    int c = ch * 32 + t;
    double m = s19[c] / 120000.0;
    double var = s19[128 + c] / 120000.0 - m * m;
    if (var < 0) var = 0;
    float A = (float)((double)g3[c] / sqrt(var + 1e-5));
    ab[t][0] = A; ab[t][1] = b3[c] - (float)m * A;
  }
  __syncthreads();
  int lane = t & 31, rg = t >> 5;
#pragma unroll 4
  for (int r = 0; r < 32; r++) {
    int h_l = r * 8 + rg;
    int h = hh * 256 + h_l;
    int n = inv[h * W_ + w];
    float v = 0.f;
    if (n >= 0) {
      float y = y19[(size_t)n * 128 + ch * 32 + lane];
      v = mishf(y * ab[lane][0] + ab[lane][1]) +
          x17[(size_t)n * 128 + ch * 32 + lane];
    }
    buf[h_l * 32 + (lane ^ (h_l & 31))] = v;
  }
  __syncthreads();
#pragma unroll 4
  for (int c_l = 0; c_l < 32; c_l++) {
    out[(size_t)(ch * 32 + c_l) * (W_ * H_) + (size_t)w * H_ + hh * 256 + t] =
        buf[t * 32 + (c_l ^ (t & 31))];
  }
}

extern "C" void kernel_launch(void* const* d_in, const int* in_sizes, int n_in,
                              void* d_out, int out_size, void* d_ws, size_t ws_size,
                              hipStream_t stream) {
  const float* voxels = (const float*)d_in[0];
  const float* vmask = (const float*)d_in[1];
  const float* bmask = (const float*)d_in[2];
  const float* W1 = (const float*)d_in[3];
  const float* g1 = (const float*)d_in[4];
  const float* b1 = (const float*)d_in[5];
  const float* W2 = (const float*)d_in[6];
  const float* g2 = (const float*)d_in[7];
  const float* b2 = (const float*)d_in[8];
  const float* W3 = (const float*)d_in[9];
  const float* g3 = (const float*)d_in[10];
  const float* b3 = (const float*)d_in[11];
  const float* W4 = (const float*)d_in[12];
  const float* g4 = (const float*)d_in[13];
  const float* b4 = (const float*)d_in[14];
  const float* Wb1 = (const float*)d_in[15];
  const float* gb1 = (const float*)d_in[16];
  const float* bb1 = (const float*)d_in[17];
  const float* Wb2 = (const float*)d_in[18];
  const float* gb2 = (const float*)d_in[19];
  const float* bb2 = (const float*)d_in[20];
  const float* Wb3 = (const float*)d_in[21];
  const float* gb3 = (const float*)d_in[22];
  const float* bb3 = (const float*)d_in[23];
  const int* bevsidx = (const int*)d_in[24];
  const int* bevcoors = (const int*)d_in[25];

  float* ws = (float*)d_ws;
  float* y1 = ws + OF_Y1;
  float* y2 = ws + OF_Y2;
  float* y34 = ws + OF_Y34;
  float* vw = ws + OF_VW;
  float* pre17 = ws + OF_PRE17;
  float* x17 = ws + OF_X17;
  float* y1819 = ws + OF_Y1819;
  int* inv = (int*)(ws + OF_INV);
  double* stats = (double*)((char*)d_ws + STATS_BYTE);

  hipMemsetAsync(stats, 0, D_TOTAL * sizeof(double), stream);
  hipMemsetAsync(inv, 0xFF, (size_t)(H_ * W_) * sizeof(int), stream);

  k_inv<<<469, 256, 0, stream>>>(bevcoors, inv);
  k1<<<3125, 256, 0, stream>>>(voxels, W1, y1, stats + D_ST1);
  k2<<<3125, 256, 0, stream>>>(y1, stats + D_ST1, g1, b1, W2, y2, stats + D_ST2);
  k3<<<3125, 256, 0, stream>>>(y2, stats + D_ST2, g2, b2, vmask, W3, y34,
                               stats + D_ST3);
  k4<<<3125, 256, 0, stream>>>(y34, stats + D_ST3, g3, b3, W4, stats + D_ST4);
  k5<<<3125, 256, 0, stream>>>(y34, stats + D_ST4, g4, b4, y2, stats + D_ST2,
                               g2, b2, vmask, vw);
  k6<<<469, 256, 0, stream>>>(vw, bevsidx, Wb1, stats + D_SB1);
  k7<<<469, 256, 0, stream>>>(vw, bevsidx, Wb1, stats + D_SB1, gb1, bb1, bmask,
                              Wb2, pre17, stats + D_SB2);
  kgemm<0><<<938, 256, 0, stream>>>(pre17, stats + D_SB2, gb2, bb2, Wb3, x17,
                                    y1819, stats + D_S18);
  kgemm<1><<<938, 256, 0, stream>>>(y1819, stats + D_S18, gb3, bb3, Wb3, nullptr,
                                    y1819, stats + D_S19);
  dim3 g10(512, 2, 4);
  k10<<<g10, 256, 0, stream>>>(y1819, x17, stats + D_S19, gb3, bb3, inv,
                               (float*)d_out);
}

// Round 9
// 1444.254 us; speedup vs baseline: 3.3235x; 1.1823x over previous
//
#include <hip/hip_runtime.h>
#include <math.h>

#define NV_   50000
#define T16_  16
#define NVT_  800000
#define NB_   120000
#define G_    16
#define P_    8
#define H_    512
#define W_    512

// ---- workspace layout (float element offsets) ----
#define OF_Y34    0ul
#define OF_Y2     51200000ul
#define OF_Y1     76800000ul
#define OF_VW     83200000ul
#define OF_INV    86400000ul
#define OF_PRE17  0ul
#define OF_X17    16000000ul
#define OF_Y1819  32000000ul
#define STATS_BYTE 346648576ul

#define D_ST1 0
#define D_ST2 16
#define D_ST3 80
#define D_ST4 208
#define D_SB1 336
#define D_SB2 592
#define D_S18 656
#define D_S19 912
#define D_TOTAL 1168

#define LB_HEAVY __launch_bounds__(256, 2)
#define LB_LIGHT __launch_bounds__(256, 4)

// k3/k4 channel-owner GEMM geometry: 2500 blocks x 20 chunks x 16 rows = 800K
#define GEMM_BLOCKS 2500
#define GEMM_CHUNKS 20

__device__ __forceinline__ float mishf(float x) {
  float e = __expf(x);
  float u = 1.0f + e;
  return x - 2.0f * x / (u * u + 1.0f);
}

template <int N>
__device__ __forceinline__ void wave_red_sum(float* v) {
#pragma unroll
  for (int d = 1; d < 64; d <<= 1) {
#pragma unroll
    for (int i = 0; i < N; i++) v[i] += __shfl_xor(v[i], d, 64);
  }
}

// ---------------- inverse scatter map ----------------
__global__ void LB_LIGHT k_inv(const int* __restrict__ coors, int* __restrict__ inv) {
  int n = blockIdx.x * 256 + threadIdx.x;
  if (n < NB_) {
    int h = coors[2 * n], w = coors[2 * n + 1];
    inv[h * W_ + w] = n;
  }
}

// ---------------- K1: y1 = voxels @ W1^T, stats(y1) ----------------
__global__ void LB_LIGHT k1(const float* __restrict__ vox, const float* __restrict__ W1,
                   float* __restrict__ y1, double* __restrict__ st) {
  __shared__ float wl[64];
  __shared__ float lst[16];
  int t = threadIdx.x;
  if (t < 64) wl[t] = W1[t];
  if (t < 16) lst[t] = 0.f;
  __syncthreads();
  size_t s = (size_t)blockIdx.x * 256 + t;
  const float4* vp = (const float4*)(vox + s * 8);
  float4 a0 = vp[0], a1 = vp[1];
  float x[8] = {a0.x, a0.y, a0.z, a0.w, a1.x, a1.y, a1.z, a1.w};
  float y[8];
#pragma unroll
  for (int o = 0; o < 8; o++) {
    float a = 0.f;
#pragma unroll
    for (int c = 0; c < 8; c++) a += x[c] * wl[o * 8 + c];
    y[o] = a;
  }
  float4* yp = (float4*)(y1 + s * 8);
  yp[0] = make_float4(y[0], y[1], y[2], y[3]);
  yp[1] = make_float4(y[4], y[5], y[6], y[7]);
  float v[16];
#pragma unroll
  for (int i = 0; i < 8; i++) { v[i] = y[i]; v[8 + i] = y[i] * y[i]; }
  wave_red_sum<16>(v);
  if ((t & 63) == 0) {
#pragma unroll
    for (int i = 0; i < 16; i++) atomicAdd(&lst[i], v[i]);
  }
  __syncthreads();
  if (t < 16) atomicAdd(&st[t], (double)lst[t]);
}

// ---------------- K2: p1=act(y1); max_T; y2 = [p1,a] @ W2^T; stats(y2) ------
__global__ void LB_HEAVY k2(const float* __restrict__ y1, const double* __restrict__ st1,
                   const float* __restrict__ g1, const float* __restrict__ b1,
                   const float* __restrict__ W2, float* __restrict__ y2,
                   double* __restrict__ st2) {
  __shared__ float wl[512];
  __shared__ float ab[8][2];
  __shared__ float lst[64];
  int t = threadIdx.x;
  wl[t] = W2[t];
  wl[256 + t] = W2[256 + t];
  if (t < 8) {
    double m = st1[t] / (double)NVT_;
    double var = st1[8 + t] / (double)NVT_ - m * m;
    if (var < 0) var = 0;
    float A = (float)((double)g1[t] / sqrt(var + 1e-5));
    ab[t][0] = A; ab[t][1] = b1[t] - (float)m * A;
  }
  if (t < 64) lst[t] = 0.f;
  __syncthreads();
  size_t s = (size_t)blockIdx.x * 256 + t;
  const float4* yp = (const float4*)(y1 + s * 8);
  float4 f0 = yp[0], f1 = yp[1];
  float in[8] = {f0.x, f0.y, f0.z, f0.w, f1.x, f1.y, f1.z, f1.w};
  float xr[16];
#pragma unroll
  for (int c = 0; c < 8; c++) xr[c] = mishf(in[c] * ab[c][0] + ab[c][1]);
#pragma unroll
  for (int c = 0; c < 8; c++) xr[8 + c] = xr[c];
#pragma unroll
  for (int d = 1; d < 16; d <<= 1) {
#pragma unroll
    for (int c = 0; c < 8; c++)
      xr[8 + c] = fmaxf(xr[8 + c], __shfl_xor(xr[8 + c], d, 64));
  }
  float yo[32];
#pragma unroll
  for (int o = 0; o < 32; o++) {
    float a = 0.f;
    const float4* wp = (const float4*)(wl + o * 16);
#pragma unroll
    for (int c4 = 0; c4 < 4; c4++) {
      float4 w4 = wp[c4];
      a += xr[c4 * 4 + 0] * w4.x + xr[c4 * 4 + 1] * w4.y +
           xr[c4 * 4 + 2] * w4.z + xr[c4 * 4 + 3] * w4.w;
    }
    yo[o] = a;
  }
  float4* op = (float4*)(y2 + s * 32);
#pragma unroll
  for (int j = 0; j < 8; j++)
    op[j] = make_float4(yo[j * 4], yo[j * 4 + 1], yo[j * 4 + 2], yo[j * 4 + 3]);
#pragma unroll
  for (int ch = 0; ch < 4; ch++) {
    float v[16];
#pragma unroll
    for (int i = 0; i < 8; i++) {
      v[i] = yo[ch * 8 + i]; v[8 + i] = v[i] * v[i];
    }
    wave_red_sum<16>(v);
    if ((t & 63) == 0) {
#pragma unroll
      for (int i = 0; i < 8; i++) {
        atomicAdd(&lst[ch * 8 + i], v[i]);
        atomicAdd(&lst[32 + ch * 8 + i], v[8 + i]);
      }
    }
  }
  __syncthreads();
  if (t < 64) atomicAdd(&st2[t], (double)lst[t]);
}

// ------- K3 (channel-owner): x2 tile in LDS; y3[o] = dot(x2, W3row[o]) ------
// Thread t owns output channel o=t&63; W3 row o lives in 16 VGPR float4s,
// loaded ONCE. Rows staged 16/chunk (= one voxel, so max-over-T is in-chunk).
__global__ void __launch_bounds__(256, 4)
k3(const float* __restrict__ y2, const double* __restrict__ st2,
   const float* __restrict__ g2, const float* __restrict__ b2,
   const float* __restrict__ vmask, const float* __restrict__ W3,
   float* __restrict__ y3, double* __restrict__ st3) {
  __shared__ float ab[32][2];
  __shared__ float x2s[16][32];
  __shared__ float xmax[32];
  __shared__ float msk[16];
  __shared__ float xs[16][64];
  __shared__ float lst[128];
  int t = threadIdx.x;
  int o = t & 63, wv = t >> 6;
  if (t < 32) {
    double m = st2[t] / (double)NVT_;
    double var = st2[32 + t] / (double)NVT_ - m * m;
    if (var < 0) var = 0;
    float A = (float)((double)g2[t] / sqrt(var + 1e-5));
    ab[t][0] = A; ab[t][1] = b2[t] - (float)m * A;
  }
  if (t < 128) lst[t] = 0.f;
  float4 w[16];
#pragma unroll
  for (int i = 0; i < 16; i++) w[i] = *(const float4*)(W3 + o * 64 + i * 4);
  __syncthreads();
  float ssum = 0.f, ssq = 0.f;
  for (int ch = 0; ch < GEMM_CHUNKS; ++ch) {
    size_t base = ((size_t)blockIdx.x * GEMM_CHUNKS + ch) * 16;
    {  // stage act(BN2(y2)): 512 floats, float2 per thread
      float2 f = *(const float2*)(y2 + base * 32 + t * 2);
      int c0 = (t * 2) & 31;
      x2s[t >> 4][(t & 15) * 2 + 0] = mishf(f.x * ab[c0][0] + ab[c0][1]);
      x2s[t >> 4][(t & 15) * 2 + 1] = mishf(f.y * ab[c0 + 1][0] + ab[c0 + 1][1]);
    }
    if (t < 16) msk[t] = vmask[base + t];
    __syncthreads();
    if (t < 32) {  // per-channel max over the voxel's 16 points (pre-mask)
      float m = x2s[0][t];
#pragma unroll
      for (int r = 1; r < 16; r++) m = fmaxf(m, x2s[r][t]);
      xmax[t] = m;
    }
    __syncthreads();
    {  // build concat tile * mask: 1024 floats, 4/thread
      int row = t >> 4, c0 = (t & 15) * 4;
      float mk = msk[row];
      if (c0 < 32) {
#pragma unroll
        for (int j = 0; j < 4; j++) xs[row][c0 + j] = x2s[row][c0 + j] * mk;
      } else {
#pragma unroll
        for (int j = 0; j < 4; j++) xs[row][c0 + j] = xmax[c0 - 32 + j] * mk;
      }
    }
    __syncthreads();
    float acc[4];
#pragma unroll
    for (int r = 0; r < 4; r++) {
      int row = wv * 4 + r;
      const float4* xp = (const float4*)xs[row];  // broadcast reads
      float a = 0.f;
#pragma unroll
      for (int i = 0; i < 16; i++) {
        float4 x4 = xp[i];
        a += x4.x * w[i].x + x4.y * w[i].y + x4.z * w[i].z + x4.w * w[i].w;
      }
      acc[r] = a;
    }
#pragma unroll
    for (int r = 0; r < 4; r++) {
      int row = wv * 4 + r;
      y3[(base + row) * 64 + o] = acc[r];
      ssum += acc[r]; ssq += acc[r] * acc[r];
    }
    __syncthreads();  // guard xs/x2s reuse
  }
  atomicAdd(&lst[o], ssum);
  atomicAdd(&lst[64 + o], ssq);
  __syncthreads();
  if (t < 128) atomicAdd(&st3[t], (double)lst[t]);
}

// ------- K4 (channel-owner): x3=act(y3) tile; y4 = x3 @ W4^T in-place -------
__global__ void __launch_bounds__(256, 4)
k4(float* y34, const double* __restrict__ st3,
   const float* __restrict__ g3, const float* __restrict__ b3,
   const float* __restrict__ W4, double* __restrict__ st4) {
  __shared__ float ab[64][2];
  __shared__ float xs[16][64];
  __shared__ float lst[128];
  int t = threadIdx.x;
  int o = t & 63, wv = t >> 6;
  if (t < 64) {
    double m = st3[t] / (double)NVT_;
    double var = st3[64 + t] / (double)NVT_ - m * m;
    if (var < 0) var = 0;
    float A = (float)((double)g3[t] / sqrt(var + 1e-5));
    ab[t][0] = A; ab[t][1] = b3[t] - (float)m * A;
  }
  if (t < 128) lst[t] = 0.f;
  float4 w[16];
#pragma unroll
  for (int i = 0; i < 16; i++) w[i] = *(const float4*)(W4 + o * 64 + i * 4);
  __syncthreads();
  float ssum = 0.f, ssq = 0.f;
  for (int ch = 0; ch < GEMM_CHUNKS; ++ch) {
    size_t base = ((size_t)blockIdx.x * GEMM_CHUNKS + ch) * 16;
    {  // stage act(BN3(y3)): 1024 floats, float4 per thread
      float4 f = *(const float4*)(y34 + base * 64 + t * 4);
      int c0 = (t * 4) & 63;
      float4 v;
      v.x = mishf(f.x * ab[c0 + 0][0] + ab[c0 + 0][1]);
      v.y = mishf(f.y * ab[c0 + 1][0] + ab[c0 + 1][1]);
      v.z = mishf(f.z * ab[c0 + 2][0] + ab[c0 + 2][1]);
      v.w = mishf(f.w * ab[c0 + 3][0] + ab[c0 + 3][1]);
      *(float4*)(&xs[t >> 4][(t & 15) * 4]) = v;
    }
    __syncthreads();
    float acc[4];
#pragma unroll
    for (int r = 0; r < 4; r++) {
      int row = wv * 4 + r;
      const float4* xp = (const float4*)xs[row];  // broadcast reads
      float a = 0.f;
#pragma unroll
      for (int i = 0; i < 16; i++) {
        float4 x4 = xp[i];
        a += x4.x * w[i].x + x4.y * w[i].y + x4.z * w[i].z + x4.w * w[i].w;
      }
      acc[r] = a;
    }
#pragma unroll
    for (int r = 0; r < 4; r++) {
      int row = wv * 4 + r;
      y34[(base + row) * 64 + o] = acc[r];  // safe: all reads done pre-barrier
      ssum += acc[r]; ssq += acc[r] * acc[r];
    }
    __syncthreads();  // guard xs reuse
  }
  atomicAdd(&lst[o], ssum);
  atomicAdd(&lst[64 + o], ssq);
  __syncthreads();
  if (t < 128) atomicAdd(&st4[t], (double)lst[t]);
}

// --- K5: recompute x2 from y2; x4=act(y4)*mask+x2; voxelwise = max_T -------
__global__ void LB_HEAVY k5(const float* __restrict__ y34, const double* __restrict__ st4,
                   const float* __restrict__ g4, const float* __restrict__ b4,
                   const float* __restrict__ y2, const double* __restrict__ st2,
                   const float* __restrict__ g2, const float* __restrict__ b2,
                   const float* __restrict__ vmask, float* __restrict__ vw) {
  __shared__ float ab4[64][2];
  __shared__ float ab2[32][2];
  int t = threadIdx.x;
  if (t < 64) {
    double m = st4[t] / (double)NVT_;
    double var = st4[64 + t] / (double)NVT_ - m * m;
    if (var < 0) var = 0;
    float A = (float)((double)g4[t] / sqrt(var + 1e-5));
    ab4[t][0] = A; ab4[t][1] = b4[t] - (float)m * A;
  } else if (t >= 128 && t < 160) {
    int c = t - 128;
    double m = st2[c] / (double)NVT_;
    double var = st2[32 + c] / (double)NVT_ - m * m;
    if (var < 0) var = 0;
    float A = (float)((double)g2[c] / sqrt(var + 1e-5));
    ab2[c][0] = A; ab2[c][1] = b2[c] - (float)m * A;
  }
  __syncthreads();
  size_t s = (size_t)blockIdx.x * 256 + t;
  int v = (int)(s >> 4), ti = t & 15;
  float msk = vmask[s];
  float xr[64];
  const float4* y2p = (const float4*)(y2 + s * 32);
#pragma unroll
  for (int j = 0; j < 8; j++) {
    float4 f = y2p[j];
    xr[j * 4 + 0] = mishf(f.x * ab2[j * 4 + 0][0] + ab2[j * 4 + 0][1]);
    xr[j * 4 + 1] = mishf(f.y * ab2[j * 4 + 1][0] + ab2[j * 4 + 1][1]);
    xr[j * 4 + 2] = mishf(f.z * ab2[j * 4 + 2][0] + ab2[j * 4 + 2][1]);
    xr[j * 4 + 3] = mishf(f.w * ab2[j * 4 + 3][0] + ab2[j * 4 + 3][1]);
  }
#pragma unroll
  for (int c = 0; c < 32; c++) xr[32 + c] = xr[c];
#pragma unroll
  for (int d = 1; d < 16; d <<= 1) {
#pragma unroll
    for (int c = 0; c < 32; c++)
      xr[32 + c] = fmaxf(xr[32 + c], __shfl_xor(xr[32 + c], d, 64));
  }
#pragma unroll
  for (int c = 0; c < 64; c++) xr[c] *= msk;
  const float4* yp = (const float4*)(y34 + s * 64);
#pragma unroll
  for (int j = 0; j < 16; j++) {
    float4 f = yp[j];
    xr[j * 4 + 0] += mishf(f.x * ab4[j * 4 + 0][0] + ab4[j * 4 + 0][1]) * msk;
    xr[j * 4 + 1] += mishf(f.y * ab4[j * 4 + 1][0] + ab4[j * 4 + 1][1]) * msk;
    xr[j * 4 + 2] += mishf(f.z * ab4[j * 4 + 2][0] + ab4[j * 4 + 2][1]) * msk;
    xr[j * 4 + 3] += mishf(f.w * ab4[j * 4 + 3][0] + ab4[j * 4 + 3][1]) * msk;
  }
#pragma unroll
  for (int d = 1; d < 16; d <<= 1) {
#pragma unroll
    for (int c = 0; c < 64; c++)
      xr[c] = fmaxf(xr[c], __shfl_xor(xr[c], d, 64));
  }
  *(float4*)(vw + (size_t)v * 64 + ti * 4) =
      make_float4(xr[ti * 4], xr[ti * 4 + 1], xr[ti * 4 + 2], xr[ti * 4 + 3]);
}

// ---------------- K6: stats of grouped einsum-1 output (no materialize) -----
__global__ void LB_HEAVY k6(const float* __restrict__ vw, const int* __restrict__ idx,
                   const float* __restrict__ Wb1, double* __restrict__ sb1) {
  __shared__ float wl[1024];
  __shared__ float lst[256];
  int t = threadIdx.x;
  for (int i = t; i < 1024; i += 256) {
    int g = i >> 6, qp = i & 63;
    wl[qp * 16 + g] = Wb1[i];
  }
  lst[t] = 0.f;
  __syncthreads();
  int g = t & 15, nl = t >> 4;
  float ss[8] = {0, 0, 0, 0, 0, 0, 0, 0}, sq[8] = {0, 0, 0, 0, 0, 0, 0, 0};
  for (int it = 0; it < 16; ++it) {
    int n = blockIdx.x * 256 + it * 16 + nl;
    if (n < NB_) {
      int id[8];
#pragma unroll
      for (int p = 0; p < 8; p++) id[p] = idx[n * 8 + p];
      float xg[4][8];
#pragma unroll
      for (int p = 0; p < 8; p++) {
        float4 f = *(const float4*)(vw + (size_t)id[p] * 64 + g * 4);
        xg[0][p] = f.x; xg[1][p] = f.y; xg[2][p] = f.z; xg[3][p] = f.w;
      }
#pragma unroll
      for (int q = 0; q < 8; q++) {
        float wq[8];
#pragma unroll
        for (int p = 0; p < 8; p++) wq[p] = wl[(q * 8 + p) * 16 + g];
#pragma unroll
        for (int c = 0; c < 4; c++) {
          float a = 0.f;
#pragma unroll
          for (int p = 0; p < 8; p++) a += xg[c][p] * wq[p];
          ss[q] += a; sq[q] += a * a;
        }
      }
    }
  }
#pragma unroll
  for (int d = 16; d < 64; d <<= 1) {
#pragma unroll
    for (int q = 0; q < 8; q++) {
      ss[q] += __shfl_xor(ss[q], d, 64);
      sq[q] += __shfl_xor(sq[q], d, 64);
    }
  }
  if ((t & 48) == 0) {
#pragma unroll
    for (int q = 0; q < 8; q++) {
      atomicAdd(&lst[g * 8 + q], ss[q]);
      atomicAdd(&lst[128 + g * 8 + q], sq[q]);
    }
  }
  __syncthreads();
  atomicAdd(&sb1[t], (double)lst[t]);
}

// ------- K7: recompute einsum1, act, bevmask, einsum2 -> pre17; stats -------
__global__ void LB_HEAVY k7(const float* __restrict__ vw, const int* __restrict__ idx,
                   const float* __restrict__ Wb1, const double* __restrict__ sb1,
                   const float* __restrict__ gb1, const float* __restrict__ bb1,
                   const float* __restrict__ bmask, const float* __restrict__ Wb2,
                   float* __restrict__ pre17, double* __restrict__ sb2) {
  __shared__ float wl[1024];
  __shared__ float w2l[256];
  __shared__ float ab[128][2];
  __shared__ float lst[64];
  int t = threadIdx.x;
  for (int i = t; i < 1024; i += 256) {
    int g = i >> 6, qp = i & 63;
    wl[qp * 16 + g] = Wb1[i];
  }
  {
    int g = t >> 4, qq = t & 15;
    w2l[qq * 16 + g] = Wb2[t];
  }
  if (t < 128) {
    double m = sb1[t] / 480000.0;
    double var = sb1[128 + t] / 480000.0 - m * m;
    if (var < 0) var = 0;
    float A = (float)((double)gb1[t] / sqrt(var + 1e-5));
    ab[t][0] = A; ab[t][1] = bb1[t] - (float)m * A;
  }
  if (t < 64) lst[t] = 0.f;
  __syncthreads();
  int g = t & 15, nl = t >> 4;
  float s2[2] = {0, 0}, q2s[2] = {0, 0};
  for (int it = 0; it < 16; ++it) {
    int n = blockIdx.x * 256 + it * 16 + nl;
    if (n < NB_) {
      int id[8];
      float bmv[8];
#pragma unroll
      for (int p = 0; p < 8; p++) { id[p] = idx[n * 8 + p]; bmv[p] = bmask[n * 8 + p]; }
      float xg[4][8];
#pragma unroll
      for (int p = 0; p < 8; p++) {
        float4 f = *(const float4*)(vw + (size_t)id[p] * 64 + g * 4);
        xg[0][p] = f.x; xg[1][p] = f.y; xg[2][p] = f.z; xg[3][p] = f.w;
      }
      float th[4][8];
#pragma unroll
      for (int q = 0; q < 8; q++) {
        float wq[8];
#pragma unroll
        for (int p = 0; p < 8; p++) wq[p] = wl[(q * 8 + p) * 16 + g];
        float A = ab[g * 8 + q][0], B = ab[g * 8 + q][1];
#pragma unroll
        for (int c = 0; c < 4; c++) {
          float a = 0.f;
#pragma unroll
          for (int p = 0; p < 8; p++) a += xg[c][p] * wq[p];
          th[c][q] = mishf(a * A + B) * bmv[q];
        }
      }
#pragma unroll
      for (int c = 0; c < 4; c++) {
        float v0 = 0.f, v1 = 0.f;
#pragma unroll
        for (int q = 0; q < 8; q++) {
          v0 += th[c][q] * w2l[q * 16 + g];
          v1 += th[c][q] * w2l[(8 + q) * 16 + g];
        }
        *(float2*)(pre17 + (size_t)n * 128 + c * 32 + g * 2) = make_float2(v0, v1);
        s2[0] += v0; q2s[0] += v0 * v0;
        s2[1] += v1; q2s[1] += v1 * v1;
      }
    }
  }
#pragma unroll
  for (int d = 16; d < 64; d <<= 1) {
#pragma unroll
    for (int j = 0; j < 2; j++) {
      s2[j] += __shfl_xor(s2[j], d, 64);
      q2s[j] += __shfl_xor(q2s[j], d, 64);
    }
  }
  if ((t & 48) == 0) {
#pragma unroll
    for (int j = 0; j < 2; j++) {
      atomicAdd(&lst[g * 2 + j], s2[j]);
      atomicAdd(&lst[32 + g * 2 + j], q2s[j]);
    }
  }
  __syncthreads();
  if (t < 64) atomicAdd(&sb2[t], (double)lst[t]);
}

// -------- K8/K9: 128x128 GEMM with fused input act (tiled in LDS) ----------
template <int MODE>
__global__ void LB_HEAVY kgemm(const float* xin, const double* __restrict__ stin,
                      const float* __restrict__ gam, const float* __restrict__ bet,
                      const float* __restrict__ Wt, float* xact_out,
                      float* yout, double* __restrict__ stout) {
  __shared__ float xs[32 * 129];
  __shared__ float wsh[128 * 33];
  __shared__ float ab[128][2];
  __shared__ float lst[256];
  int t = threadIdx.x;
  const int nch = (MODE == 0) ? 32 : 128;
  const double den = (MODE == 0) ? 480000.0 : 120000.0;
  if (t < nch) {
    double m = stin[t] / den;
    double var = stin[nch + t] / den - m * m;
    if (var < 0) var = 0;
    float A = (float)((double)gam[t] / sqrt(var + 1e-5));
    ab[t][0] = A; ab[t][1] = bet[t] - (float)m * A;
  }
  lst[t] = 0.f;
  __syncthreads();
  int s0 = blockIdx.x * 128;
  int oc = t & 7, sc = t >> 3;
  int cl = t & 31, sl8 = t >> 5;
  float acc[64];
#pragma unroll
  for (int i = 0; i < 64; i++) acc[i] = 0.f;
  for (int cb = 0; cb < 128; cb += 32) {
#pragma unroll
    for (int r = 0; r < 16; r++) {
      int slocal = r * 8 + sl8;
      int sg = s0 + slocal;
      float v = 0.f;
      if (sg < NB_) {
        float h = xin[(size_t)sg * 128 + cb + cl];
        if (MODE == 0) {
          v = mishf(h * ab[cl][0] + ab[cl][1]);
          xact_out[(size_t)sg * 128 + cb + cl] = v;
        } else {
          v = mishf(h * ab[cb + cl][0] + ab[cb + cl][1]);
        }
      }
      xs[cl * 129 + slocal] = v;
    }
#pragma unroll
    for (int r = 0; r < 16; r++) {
      int o = r * 8 + sl8;
      wsh[o * 33 + cl] = Wt[o * 128 + cb + cl];
    }
    __syncthreads();
#pragma unroll 4
    for (int c = 0; c < 32; c++) {
      float xv[4];
#pragma unroll
      for (int i = 0; i < 4; i++) xv[i] = xs[c * 129 + sc * 4 + i];
#pragma unroll
      for (int k = 0; k < 16; k++) {
        float wv = wsh[(k * 8 + oc) * 33 + c];
#pragma unroll
        for (int i = 0; i < 4; i++) acc[k * 4 + i] += wv * xv[i];
      }
    }
    __syncthreads();
  }
  float ssum[16], ssq[16];
#pragma unroll
  for (int k = 0; k < 16; k++) { ssum[k] = 0.f; ssq[k] = 0.f; }
#pragma unroll
  for (int i = 0; i < 4; i++) {
    int sg = s0 + sc * 4 + i;
    if (sg < NB_) {
#pragma unroll
      for (int k = 0; k < 16; k++) {
        float v = acc[k * 4 + i];
        yout[(size_t)sg * 128 + k * 8 + oc] = v;
        ssum[k] += v; ssq[k] += v * v;
      }
    }
  }
#pragma unroll
  for (int d = 8; d < 64; d <<= 1) {
#pragma unroll
    for (int k = 0; k < 16; k++) {
      ssum[k] += __shfl_xor(ssum[k], d, 64);
      ssq[k] += __shfl_xor(ssq[k], d, 64);
    }
  }
  if ((t & 63) < 8) {
#pragma unroll
    for (int k = 0; k < 16; k++) {
      atomicAdd(&lst[k * 8 + oc], ssum[k]);
      atomicAdd(&lst[128 + k * 8 + oc], ssq[k]);
    }
  }
  __syncthreads();
  atomicAdd(&stout[t], (double)lst[t]);
}

// ------- K10: x19 = act(y19)+x17, transposed coalesced write of output ------
__global__ void LB_LIGHT k10(const float* __restrict__ y19, const float* __restrict__ x17,
                    const double* __restrict__ s19, const float* __restrict__ g3,
                    const float* __restrict__ b3, const int* __restrict__ inv,
                    float* __restrict__ out) {
  __shared__ float buf[256 * 32];
  __shared__ float ab[32][2];
  int t = threadIdx.x;
  int w = blockIdx.x, hh = blockIdx.y, ch = blockIdx.z;
  if (t < 32) {
    int c = ch * 32 + t;
    double m = s19[c] / 120000.0;
    double var = s19[128 + c] / 120000.0 - m * m;
    if (var < 0) var = 0;
    float A = (float)((double)g3[c] / sqrt(var + 1e-5));
    ab[t][0] = A; ab[t][1] = b3[c] - (float)m * A;
  }
  __syncthreads();
  int lane = t & 31, rg = t >> 5;
#pragma unroll 4
  for (int r = 0; r < 32; r++) {
    int h_l = r * 8 + rg;
    int h = hh * 256 + h_l;
    int n = inv[h * W_ + w];
    float v = 0.f;
    if (n >= 0) {
      float y = y19[(size_t)n * 128 + ch * 32 + lane];
      v = mishf(y * ab[lane][0] + ab[lane][1]) +
          x17[(size_t)n * 128 + ch * 32 + lane];
    }
    buf[h_l * 32 + (lane ^ (h_l & 31))] = v;
  }
  __syncthreads();
#pragma unroll 4
  for (int c_l = 0; c_l < 32; c_l++) {
    out[(size_t)(ch * 32 + c_l) * (W_ * H_) + (size_t)w * H_ + hh * 256 + t] =
        buf[t * 32 + (c_l ^ (t & 31))];
  }
}

extern "C" void kernel_launch(void* const* d_in, const int* in_sizes, int n_in,
                              void* d_out, int out_size, void* d_ws, size_t ws_size,
                              hipStream_t stream) {
  const float* voxels = (const float*)d_in[0];
  const float* vmask = (const float*)d_in[1];
  const float* bmask = (const float*)d_in[2];
  const float* W1 = (const float*)d_in[3];
  const float* g1 = (const float*)d_in[4];
  const float* b1 = (const float*)d_in[5];
  const float* W2 = (const float*)d_in[6];
  const float* g2 = (const float*)d_in[7];
  const float* b2 = (const float*)d_in[8];
  const float* W3 = (const float*)d_in[9];
  const float* g3 = (const float*)d_in[10];
  const float* b3 = (const float*)d_in[11];
  const float* W4 = (const float*)d_in[12];
  const float* g4 = (const float*)d_in[13];
  const float* b4 = (const float*)d_in[14];
  const float* Wb1 = (const float*)d_in[15];
  const float* gb1 = (const float*)d_in[16];
  const float* bb1 = (const float*)d_in[17];
  const float* Wb2 = (const float*)d_in[18];
  const float* gb2 = (const float*)d_in[19];
  const float* bb2 = (const float*)d_in[20];
  const float* Wb3 = (const float*)d_in[21];
  const float* gb3 = (const float*)d_in[22];
  const float* bb3 = (const float*)d_in[23];
  const int* bevsidx = (const int*)d_in[24];
  const int* bevcoors = (const int*)d_in[25];

  float* ws = (float*)d_ws;
  float* y1 = ws + OF_Y1;
  float* y2 = ws + OF_Y2;
  float* y34 = ws + OF_Y34;
  float* vw = ws + OF_VW;
  float* pre17 = ws + OF_PRE17;
  float* x17 = ws + OF_X17;
  float* y1819 = ws + OF_Y1819;
  int* inv = (int*)(ws + OF_INV);
  double* stats = (double*)((char*)d_ws + STATS_BYTE);

  hipMemsetAsync(stats, 0, D_TOTAL * sizeof(double), stream);
  hipMemsetAsync(inv, 0xFF, (size_t)(H_ * W_) * sizeof(int), stream);

  k_inv<<<469, 256, 0, stream>>>(bevcoors, inv);
  k1<<<3125, 256, 0, stream>>>(voxels, W1, y1, stats + D_ST1);
  k2<<<3125, 256, 0, stream>>>(y1, stats + D_ST1, g1, b1, W2, y2, stats + D_ST2);
  k3<<<GEMM_BLOCKS, 256, 0, stream>>>(y2, stats + D_ST2, g2, b2, vmask, W3, y34,
                                      stats + D_ST3);
  k4<<<GEMM_BLOCKS, 256, 0, stream>>>(y34, stats + D_ST3, g3, b3, W4,
                                      stats + D_ST4);
  k5<<<3125, 256, 0, stream>>>(y34, stats + D_ST4, g4, b4, y2, stats + D_ST2,
                               g2, b2, vmask, vw);
  k6<<<469, 256, 0, stream>>>(vw, bevsidx, Wb1, stats + D_SB1);
  k7<<<469, 256, 0, stream>>>(vw, bevsidx, Wb1, stats + D_SB1, gb1, bb1, bmask,
                              Wb2, pre17, stats + D_SB2);
  kgemm<0><<<938, 256, 0, stream>>>(pre17, stats + D_SB2, gb2, bb2, Wb3, x17,
                                    y1819, stats + D_S18);
  kgemm<1><<<938, 256, 0, stream>>>(y1819, stats + D_S18, gb3, bb3, Wb3, nullptr,
                                    y1819, stats + D_S19);
  dim3 g10(512, 2, 4);
  k10<<<g10, 256, 0, stream>>>(y1819, x17, stats + D_S19, gb3, bb3, inv,
                               (float*)d_out);
}